// Round 6
// baseline (600.630 us; speedup 1.0000x reference)
//
#include <hip/hip_runtime.h>
#include <hip/hip_bf16.h>
#include <stdint.h>

// Shapes: B=32, L=256, D=1024, ALIGN=1024, FF=2048, NC=3
// Precision plan:
//  - F proj (split bf16x3), E scores (split bf16x3): the softmax-sensitive path
//  - attn, betas/alphas: fp16 single, V = tanh(Cat@W_G): fp16 single + colsum
//  - classifier: fp32 VALU skinny GEMM (more accurate than split-bf16x3,
//    and W1/W2 are memory-bound: 0.5 GFLOP vs 48 MB of weights)

typedef __attribute__((ext_vector_type(8))) short    short8_t;   // 8 bf16
typedef __attribute__((ext_vector_type(4))) float    float4_t;
typedef __attribute__((ext_vector_type(8))) _Float16 half8_t;
typedef __attribute__((ext_vector_type(4))) _Float16 half4_t;

#define DEVI static __device__ __forceinline__

DEVI short f2bf(float f) {
  union { float f; unsigned u; } v; v.f = f;
  unsigned r = v.u + 0x7fffu + ((v.u >> 16) & 1u);   // RNE
  return (short)(r >> 16);
}
DEVI float bf2f(short s) {
  union { unsigned u; float f; } v;
  v.u = ((unsigned)(unsigned short)s) << 16;
  return v.f;
}
DEVI void split2(float x, short& hi, short& lo) {
  hi = f2bf(x);
  lo = f2bf(x - bf2f(hi));
}
DEVI float fast_tanh(float x) {
  float e = __expf(2.0f * x);
  return 1.0f - 2.0f / (e + 1.0f);
}
DEVI void gload16(const void* g, void* l) {
  // async global->LDS, 16B/lane; LDS dest = wave-uniform base + lane*16
  __builtin_amdgcn_global_load_lds(
      (const __attribute__((address_space(1))) void*)g,
      (__attribute__((address_space(3))) void*)l, 16, 0, 0);
}

// ---------------------------------------------------------------------------
// Split-bf16 NT GEMM (A=Ah+Al, B=Bh+Bl), 128x128 tile, BK=32, 4 waves,
// 3 MFMAs per product (hh,hl,lh). blockIdx.z = batch*kslices + kslice.
// OUT_MODE: 0 = fp32 atomicAdd (split-K accumulation; C pre-zeroed)
//           1 = split bf16 store (optional tanh)
// global_load_lds width=16 staging; unpadded [128][32] planes, linear LDS
// dest (row t>>2, slot t&3), pre-swizzled global source chunk (t&3)^((t>>3)&3)
// => slot s of row r holds chunk s^((r>>1)&3); reads at slot q^((m15>>1)&3).
// ---------------------------------------------------------------------------
template <int DO_TANH, int OUT_MODE>
__global__ __launch_bounds__(256) void gemm_nt_split(
    const short* __restrict__ Ah, const short* __restrict__ Al, int lda, long sA,
    const short* __restrict__ Bh, const short* __restrict__ Bl, int ldb, long sB,
    void* __restrict__ Ch, void* __restrict__ Cl, int ldc, long sC,
    int M, int K, int kslices)
{
  __shared__ __align__(16) short Ash[128 * 32];
  __shared__ __align__(16) short Asl[128 * 32];
  __shared__ __align__(16) short Bsh[128 * 32];
  __shared__ __align__(16) short Bsl[128 * 32];

  const int z  = blockIdx.z;
  const int zb = z / kslices;
  const int zk = z - zb * kslices;
  const int Ksub = K / kslices;
  const int kbeg = zk * Ksub, kend = kbeg + Ksub;

  Ah += (size_t)zb * sA;  Al += (size_t)zb * sA;
  Bh += (size_t)zb * sB;  Bl += (size_t)zb * sB;

  const int row0 = blockIdx.x * 128;
  const int col0 = blockIdx.y * 128;

  const int t    = threadIdx.x;
  const int lane = t & 63;
  const int wave = t >> 6;
  const int wr = wave >> 1, wc = wave & 1;
  const int m15 = lane & 15, q = lane >> 4;

  const int schk = ((t & 3) ^ ((t >> 3) & 3)) * 8;
  const short* pAh = Ah + (size_t)(row0 + (t >> 2)) * lda + kbeg + schk;
  const short* pAl = Al + (size_t)(row0 + (t >> 2)) * lda + kbeg + schk;
  const short* pBh = Bh + (size_t)(col0 + (t >> 2)) * ldb + kbeg + schk;
  const short* pBl = Bl + (size_t)(col0 + (t >> 2)) * ldb + kbeg + schk;
  const size_t a64 = (size_t)64 * lda, b64 = (size_t)64 * ldb;
  short* lAh = &Ash[wave * 512];
  short* lAl = &Asl[wave * 512];
  short* lBh = &Bsh[wave * 512];
  short* lBl = &Bsl[wave * 512];

  const int fs2 = (q ^ ((m15 >> 1) & 3)) * 8;

  float4_t acc[4][4];
#pragma unroll
  for (int i = 0; i < 4; ++i)
#pragma unroll
    for (int j = 0; j < 4; ++j) acc[i][j] = (float4_t)0.0f;

  for (int k0 = kbeg; k0 < kend; k0 += 32) {
    gload16(pAh, lAh);  gload16(pAh + a64, lAh + 2048);
    gload16(pAl, lAl);  gload16(pAl + a64, lAl + 2048);
    gload16(pBh, lBh);  gload16(pBh + b64, lBh + 2048);
    gload16(pBl, lBl);  gload16(pBl + b64, lBl + 2048);
    pAh += 32; pAl += 32; pBh += 32; pBl += 32;
    __syncthreads();

    short8_t ah[4], al[4];
#pragma unroll
    for (int i = 0; i < 4; ++i) {
      const int ra = (wr * 64 + i * 16 + m15) * 32 + fs2;
      ah[i] = *(const short8_t*)&Ash[ra];
      al[i] = *(const short8_t*)&Asl[ra];
    }
#pragma unroll
    for (int j = 0; j < 4; ++j) {
      const int rb = (wc * 64 + j * 16 + m15) * 32 + fs2;
      short8_t bh = *(const short8_t*)&Bsh[rb];
      short8_t bl = *(const short8_t*)&Bsl[rb];
#pragma unroll
      for (int i = 0; i < 4; ++i) {
        acc[i][j] = __builtin_amdgcn_mfma_f32_16x16x32_bf16(ah[i], bh, acc[i][j], 0, 0, 0);
        acc[i][j] = __builtin_amdgcn_mfma_f32_16x16x32_bf16(ah[i], bl, acc[i][j], 0, 0, 0);
        acc[i][j] = __builtin_amdgcn_mfma_f32_16x16x32_bf16(al[i], bh, acc[i][j], 0, 0, 0);
      }
    }
    __syncthreads();
  }

  short* Chs = (short*)Ch + (size_t)zb * sC;
  short* Cls = (short*)Cl + (size_t)zb * sC;
  float* Cf  = (float*)Ch + (size_t)zb * sC;
#pragma unroll
  for (int i = 0; i < 4; ++i) {
#pragma unroll
    for (int r = 0; r < 4; ++r) {
      int gm = row0 + wr * 64 + i * 16 + q * 4 + r;
      if (gm < M) {
#pragma unroll
        for (int j = 0; j < 4; ++j) {
          int gn = col0 + wc * 64 + j * 16 + m15;
          float v = acc[i][j][r];
          if (DO_TANH) v = fast_tanh(v);
          if (OUT_MODE == 0) {
            atomicAdd(&Cf[(size_t)gm * ldc + gn], v);
          } else {
            short hi, lo; split2(v, hi, lo);
            Chs[(size_t)gm * ldc + gn] = hi;
            Cls[(size_t)gm * ldc + gn] = lo;
          }
        }
      }
    }
  }
}

// ---------------------------------------------------------------------------
// fp16 single-pass NT GEMM, BK=64, async global_load_lds staging, XOR
// chunk-swizzled unpadded LDS (0 bank conflicts). fp16 store.
// B batch index = z ^ bxor (lets one launch cover betas (z<32, B=H^T) and
// alphas (z>=32, B=P^T) with PHbT layout [P^T batches | H^T batches]).
// K % 64 == 0.
// ---------------------------------------------------------------------------
__global__ __launch_bounds__(256) void gemm_f16(
    const _Float16* __restrict__ A, int lda, long sA,
    const _Float16* __restrict__ B, int ldb, long sB,
    _Float16* __restrict__ C, int ldc, long sC,
    int K, int bxor)
{
  __shared__ __align__(16) _Float16 As[2 * 128 * 32];
  __shared__ __align__(16) _Float16 Bs[2 * 128 * 32];

  const int z = blockIdx.z;
  A += (size_t)z * sA;
  B += (size_t)(z ^ bxor) * sB;

  const int row0 = blockIdx.x * 128;
  const int col0 = blockIdx.y * 128;
  const int t = threadIdx.x, lane = t & 63, wave = t >> 6;
  const int wr = wave >> 1, wc = wave & 1;
  const int m15 = lane & 15, q = lane >> 4;

  const int srow = wave * 32 + (lane >> 2);
  const int cg   = ((lane & 3) ^ ((lane >> 3) & 3)) * 8;
  const _Float16* gA0 = A + (size_t)(row0 + srow) * lda + cg;
  const _Float16* gA1 = gA0 + (size_t)16 * lda;
  const _Float16* gB0 = B + (size_t)(col0 + srow) * ldb + cg;
  const _Float16* gB1 = gB0 + (size_t)16 * ldb;
  const _Float16* gA0b = gA0 + 32;
  const _Float16* gA1b = gA1 + 32;
  const _Float16* gB0b = gB0 + 32;
  const _Float16* gB1b = gB1 + 32;
  _Float16* lA0  = &As[(wave * 32) * 32];
  _Float16* lA1  = &As[(wave * 32 + 16) * 32];
  _Float16* lB0  = &Bs[(wave * 32) * 32];
  _Float16* lB1  = &Bs[(wave * 32 + 16) * 32];
  _Float16* lA0b = lA0 + 4096;
  _Float16* lA1b = lA1 + 4096;
  _Float16* lB0b = lB0 + 4096;
  _Float16* lB1b = lB1 + 4096;

  const int fs = (q ^ ((m15 >> 1) & 3)) * 8;
  int aoff[4], boff[4];
#pragma unroll
  for (int i = 0; i < 4; ++i) {
    aoff[i] = (wr * 64 + i * 16 + m15) * 32 + fs;
    boff[i] = (wc * 64 + i * 16 + m15) * 32 + fs;
  }

  float4_t acc[4][4];
#pragma unroll
  for (int i = 0; i < 4; ++i)
#pragma unroll
    for (int j = 0; j < 4; ++j) acc[i][j] = (float4_t)0.0f;

  for (int k0 = 0; k0 < K; k0 += 64) {
    gload16(gA0, lA0);  gload16(gA1, lA1);
    gload16(gB0, lB0);  gload16(gB1, lB1);
    gload16(gA0b, lA0b); gload16(gA1b, lA1b);
    gload16(gB0b, lB0b); gload16(gB1b, lB1b);
    gA0 += 64; gA1 += 64; gB0 += 64; gB1 += 64;
    gA0b += 64; gA1b += 64; gB0b += 64; gB1b += 64;
    __syncthreads();

#pragma unroll
    for (int h = 0; h < 2; ++h) {
      half8_t af[4], bfr[4];
#pragma unroll
      for (int i = 0; i < 4; ++i) af[i]  = *(const half8_t*)&As[h * 4096 + aoff[i]];
#pragma unroll
      for (int j = 0; j < 4; ++j) bfr[j] = *(const half8_t*)&Bs[h * 4096 + boff[j]];
#pragma unroll
      for (int i = 0; i < 4; ++i)
#pragma unroll
        for (int j = 0; j < 4; ++j)
          acc[i][j] = __builtin_amdgcn_mfma_f32_16x16x32_f16(af[i], bfr[j], acc[i][j], 0, 0, 0);
    }
    __syncthreads();
  }

  {
    _Float16* Cp = C + (size_t)z * sC;
#pragma unroll
    for (int i = 0; i < 4; ++i)
#pragma unroll
      for (int r = 0; r < 4; ++r) {
        int gm = row0 + wr * 64 + i * 16 + q * 4 + r;
#pragma unroll
        for (int j = 0; j < 4; ++j) {
          int gn = col0 + wc * 64 + j * 16 + m15;
          Cp[(size_t)gm * ldc + gn] = (_Float16)acc[i][j][r];
        }
      }
  }
}

// ---------------------------------------------------------------------------
// V-GEMM: fp16 NT, 256x256 tile, BK=32, 512 threads = 8 waves (2M x 4N),
// 4-deep LDS ring (4 x 32 KiB), tile t+2 staged during tile t, ONE barrier
// per K-tile, counted vmcnt(4). Conflict-free chunk swizzle (0 measured).
// 843 TF = documented plain-HIP template ceiling for this shape class (m248).
// Fused tanh + column-sum epilogue -> agg.
// ---------------------------------------------------------------------------
__global__ __launch_bounds__(512, 2) void gemm_f16_sum8(
    const _Float16* __restrict__ A, int lda,
    const _Float16* __restrict__ B, int ldb,
    int K, float* __restrict__ agg)
{
  __shared__ __align__(16) _Float16 LDS[4][2 * 256 * 32];

  const int row0 = blockIdx.x * 256;
  const int col0 = blockIdx.y * 256;
  const int tid  = threadIdx.x;
  const int lane = tid & 63, wave = tid >> 6;
  const int wr = wave >> 2, wc = wave & 3;     // 2 M-waves x 4 N-waves
  const int m15 = lane & 15, q = lane >> 4;
  const int nt = K / 32;

  const int srow = wave * 32 + (lane >> 2);
  const int cg   = ((lane & 3) ^ ((lane >> 3) & 3)) * 8;
  const _Float16* gA = A + (size_t)(row0 + srow) * lda + cg;
  const _Float16* gB = B + (size_t)(col0 + srow) * ldb + cg;

  auto stageA = [&](int t) {
    const _Float16* g = gA + t * 32;
    _Float16* l = &LDS[t & 3][wave * 1024];
    gload16(g, l);
    gload16(g + (size_t)16 * lda, l + 512);
  };
  auto stageB = [&](int t) {
    const _Float16* g = gB + t * 32;
    _Float16* l = &LDS[t & 3][8192 + wave * 1024];
    gload16(g, l);
    gload16(g + (size_t)16 * ldb, l + 512);
  };

  const int xq = (q ^ ((m15 >> 1) & 3)) * 8;
  int aoff[8], boff[4];
#pragma unroll
  for (int i = 0; i < 8; ++i)
    aoff[i] = (wr * 128 + i * 16 + m15) * 32 + xq;
#pragma unroll
  for (int j = 0; j < 4; ++j)
    boff[j] = 8192 + (wc * 64 + j * 16 + m15) * 32 + xq;

  float4_t acc[8][4];
#pragma unroll
  for (int i = 0; i < 8; ++i)
#pragma unroll
    for (int j = 0; j < 4; ++j) acc[i][j] = (float4_t)0.0f;

  stageA(0); stageB(0);
  stageA(1); stageB(1);
  asm volatile("s_waitcnt vmcnt(4)");
  __builtin_amdgcn_s_barrier();

  for (int t = 0; t < nt; ++t) {
    const _Float16* buf = &LDS[t & 3][0];
    __builtin_amdgcn_sched_barrier(0);

    half8_t a0[4], a1[4], bb[4];
#pragma unroll
    for (int i = 0; i < 4; ++i) a0[i] = *(const half8_t*)&buf[aoff[i]];
#pragma unroll
    for (int j = 0; j < 4; ++j) bb[j] = *(const half8_t*)&buf[boff[j]];
#pragma unroll
    for (int i = 0; i < 4; ++i) a1[i] = *(const half8_t*)&buf[aoff[4 + i]];

    if (t + 2 < nt) { stageA(t + 2); stageB(t + 2); }

    __builtin_amdgcn_s_setprio(1);
#pragma unroll
    for (int i = 0; i < 4; ++i)
#pragma unroll
      for (int j = 0; j < 4; ++j)
        acc[i][j] = __builtin_amdgcn_mfma_f32_16x16x32_f16(a0[i], bb[j], acc[i][j], 0, 0, 0);
#pragma unroll
    for (int i = 0; i < 4; ++i)
#pragma unroll
      for (int j = 0; j < 4; ++j)
        acc[4 + i][j] = __builtin_amdgcn_mfma_f32_16x16x32_f16(a1[i], bb[j], acc[4 + i][j], 0, 0, 0);
    __builtin_amdgcn_s_setprio(0);

    __builtin_amdgcn_sched_barrier(0);
    if (t + 2 < nt) {
      asm volatile("s_waitcnt vmcnt(4)");
    } else if (t + 1 < nt) {
      asm volatile("s_waitcnt vmcnt(0)");
    }
    __builtin_amdgcn_s_barrier();
  }

  // ---- epilogue: tanh + column-sum -> agg[b][half*2048 + col] ----
  const int half_ = row0 >= 8192;
  const int b     = (row0 & 8191) >> 8;
#pragma unroll
  for (int j = 0; j < 4; ++j) {
    float s = 0.0f;
#pragma unroll
    for (int i = 0; i < 8; ++i)
#pragma unroll
      for (int r = 0; r < 4; ++r) s += fast_tanh(acc[i][j][r]);
    s += __shfl_xor(s, 16);
    s += __shfl_xor(s, 32);
    if (q == 0) {
      int col = col0 + wc * 64 + j * 16 + m15;
      atomicAdd(&agg[(size_t)b * 4096 + half_ * 2048 + col], s);
    }
  }
}

// --- fp32 -> split bf16 transpose: out[c][r] (used for W_F) ---
__global__ __launch_bounds__(256) void transpose_split(
    const float* __restrict__ in, short* __restrict__ oh, short* __restrict__ ol,
    int R, int C)
{
  __shared__ float tile[32][33];
  const int tx = threadIdx.x & 31, ty = threadIdx.x >> 5;
  const int c0 = blockIdx.x * 32, r0 = blockIdx.y * 32;
#pragma unroll
  for (int i = 0; i < 4; ++i) {
    int r = ty + i * 8;
    tile[r][tx] = in[(size_t)(r0 + r) * C + c0 + tx];
  }
  __syncthreads();
#pragma unroll
  for (int i = 0; i < 4; ++i) {
    int cc = ty + i * 8;
    float v = tile[tx][cc];
    short hi, lo; split2(v, hi, lo);
    size_t o = (size_t)(c0 + cc) * R + r0 + tx;
    oh[o] = hi;
    ol[o] = lo;
  }
}

// --- fp32 -> fp16 transpose: out[c][r] (used for W_G) ---
__global__ __launch_bounds__(256) void transpose_f16(
    const float* __restrict__ in, _Float16* __restrict__ out, int R, int C)
{
  __shared__ float tile[32][33];
  const int tx = threadIdx.x & 31, ty = threadIdx.x >> 5;
  const int c0 = blockIdx.x * 32, r0 = blockIdx.y * 32;
#pragma unroll
  for (int i = 0; i < 4; ++i) {
    int r = ty + i * 8;
    tile[r][tx] = in[(size_t)(r0 + r) * C + c0 + tx];
  }
  __syncthreads();
#pragma unroll
  for (int i = 0; i < 4; ++i) {
    int cc = ty + i * 8;
    out[(size_t)(c0 + cc) * R + r0 + tx] = (_Float16)tile[tx][cc];
  }
}

// --- fp16 [256x256] batched transpose (attn -> attnT) ---
__global__ __launch_bounds__(256) void transpose_b2b(
    const short* __restrict__ in, short* __restrict__ out,
    int R, int C, long sIn, long sOut)
{
  __shared__ short tile[32][33];
  in  += (size_t)blockIdx.z * sIn;
  out += (size_t)blockIdx.z * sOut;
  const int tx = threadIdx.x & 31, ty = threadIdx.x >> 5;
  const int c0 = blockIdx.x * 32, r0 = blockIdx.y * 32;
#pragma unroll
  for (int i = 0; i < 4; ++i) {
    int r = ty + i * 8;
    tile[r][tx] = in[(size_t)(r0 + r) * C + c0 + tx];
  }
  __syncthreads();
#pragma unroll
  for (int i = 0; i < 4; ++i) {
    int cc = ty + i * 8;
    out[(size_t)(c0 + cc) * R + r0 + tx] = tile[tx][cc];
  }
}

// ---------------------------------------------------------------------------
// Fused input conversion + transpose (replaces conv_in + transpose_f16_ph):
// one pass over P/H fp32 producing (a) split bf16 planes [row][1024],
// (b) fp16 Cat left half [row][2048], (c) fp16 per-batch transpose
// PHbT[z][1024][256] (z<32 = P^T batches, z>=32 = H^T batches).
// grid (32, 8, 64): x = 32-col tile over 1024, y = 32-row tile over 256,
// z = batch (0..31 P, 32..63 H). Saves one full 64 MB read of P/H.
// ---------------------------------------------------------------------------
__global__ __launch_bounds__(256) void conv_in_t(
    const float* __restrict__ P, const float* __restrict__ Hh,
    short* __restrict__ oh, short* __restrict__ ol,
    _Float16* __restrict__ cat, _Float16* __restrict__ phbt)
{
  __shared__ float tile[32][33];
  const int zb   = blockIdx.z;
  const int half = zb >> 5;
  const int b    = zb & 31;
  const float* in = (half ? Hh : P) + (size_t)b * 256 * 1024;
  const int c0 = blockIdx.x * 32;   // col in [0,1024)
  const int r0 = blockIdx.y * 32;   // row in [0,256)
  const int tx = threadIdx.x & 31, ty = threadIdx.x >> 5;
  const size_t rowbase = (size_t)half * 8192 + (size_t)b * 256;
#pragma unroll
  for (int i = 0; i < 4; ++i) {
    int r = ty + i * 8;
    float v = in[(size_t)(r0 + r) * 1024 + c0 + tx];
    tile[r][tx] = v;
    short hi, lo; split2(v, hi, lo);
    size_t o = (rowbase + r0 + r) * 1024 + c0 + tx;
    oh[o] = hi;
    ol[o] = lo;
    cat[(rowbase + r0 + r) * 2048 + c0 + tx] = (_Float16)v;
  }
  __syncthreads();
  _Float16* op = phbt + (size_t)zb * 1024 * 256;
#pragma unroll
  for (int i = 0; i < 4; ++i) {
    int cc = ty + i * 8;
    op[(size_t)(c0 + cc) * 256 + r0 + tx] = (_Float16)tile[tx][cc];
  }
}

__global__ __launch_bounds__(256) void zero_f32(float* __restrict__ p, int n)
{
  int i = blockIdx.x * 256 + threadIdx.x;
  if (i < n) p[i] = 0.0f;
}

// --- softmax over rows of 256 (one wave per row), fp32 -> fp16 ---
__global__ __launch_bounds__(256) void softmax_rows(
    const float* __restrict__ e, _Float16* __restrict__ attn)
{
  const int row  = blockIdx.x * 4 + (threadIdx.x >> 6);
  const int lane = threadIdx.x & 63;
  const float4 v = *(const float4*)&e[(size_t)row * 256 + lane * 4];
  float m = fmaxf(fmaxf(v.x, v.y), fmaxf(v.z, v.w));
#pragma unroll
  for (int off = 32; off; off >>= 1) m = fmaxf(m, __shfl_xor(m, off));
  float e0 = __expf(v.x - m), e1 = __expf(v.y - m);
  float e2 = __expf(v.z - m), e3 = __expf(v.w - m);
  float s = e0 + e1 + e2 + e3;
#pragma unroll
  for (int off = 32; off; off >>= 1) s += __shfl_xor(s, off);
  float inv = 1.0f / s;
  half4_t o;
  o.x = (_Float16)(e0 * inv); o.y = (_Float16)(e1 * inv);
  o.z = (_Float16)(e2 * inv); o.w = (_Float16)(e3 * inv);
  *(half4_t*)&attn[(size_t)row * 256 + lane * 4] = o;
}

// ---------------------------------------------------------------------------
// Skinny fp32 GEMM: out[32][N] += A[32][K-slice] @ B[K-slice][N], atomic out.
// grid (N/64, K/256); block 256 threads. A-slice (32x256 fp32 = 32 KB) in
// LDS (broadcast reads, free); wave w owns m rows w*8..w*8+7, lane l owns
// col n0+l; B rows read coalesced (64 x 4B = 256 B per wave per k).
// Classifier is memory-bound on W (48 MB total): VALU fp32 beats the old
// transpose+split+padded-MFMA chain (96+ MB traffic, 75% wasted MFMA).
// ---------------------------------------------------------------------------
__global__ __launch_bounds__(256) void skinny_gemm(
    const float* __restrict__ A, const float* __restrict__ B,
    float* __restrict__ out, int N, int K)
{
  __shared__ float Asl[32][256];
  const int n0 = blockIdx.x * 64;
  const int k0 = blockIdx.y * 256;
  const int t  = threadIdx.x;
  for (int i = t; i < 32 * 256; i += 256) {
    int m = i >> 8, k = i & 255;
    Asl[m][k] = A[(size_t)m * K + k0 + k];
  }
  __syncthreads();
  const int l = t & 63, w = t >> 6;
  const int n = n0 + l;
  float acc[8] = {0.f, 0.f, 0.f, 0.f, 0.f, 0.f, 0.f, 0.f};
  const float* Bp = B + (size_t)k0 * N + n;
  for (int k = 0; k < 256; ++k) {
    float bv = Bp[(size_t)k * N];
#pragma unroll
    for (int m = 0; m < 8; ++m)
      acc[m] += Asl[w * 8 + m][k] * bv;
  }
#pragma unroll
  for (int m = 0; m < 8; ++m)
    atomicAdd(&out[(size_t)(w * 8 + m) * N + n], acc[m]);
}

// --- a1 = tanh(c + bias), fp32 out ---
__global__ __launch_bounds__(256) void bias_tanh_f32(
    const float* __restrict__ c, const float* __restrict__ bias,
    float* __restrict__ o, int n)
{
  int i = blockIdx.x * 256 + threadIdx.x;
  if (i < n) o[i] = fast_tanh(c[i] + bias[i & 2047]);
}

// --- logits: block b: out[b][0..2] = tanh(c2f[b]+b2) @ W3 + b3 ---
__global__ __launch_bounds__(256) void logits2(
    const float* __restrict__ c2f, const float* __restrict__ b2,
    const float* __restrict__ W3, const float* __restrict__ b3,
    float* __restrict__ out)
{
  const int b = blockIdx.x, t = threadIdx.x;
  float p0 = 0.f, p1 = 0.f, p2 = 0.f;
  for (int k = t; k < 2048; k += 256) {
    float a = fast_tanh(c2f[b * 2048 + k] + b2[k]);
    p0 += a * W3[k * 3 + 0];
    p1 += a * W3[k * 3 + 1];
    p2 += a * W3[k * 3 + 2];
  }
#pragma unroll
  for (int off = 32; off; off >>= 1) {
    p0 += __shfl_xor(p0, off);
    p1 += __shfl_xor(p1, off);
    p2 += __shfl_xor(p2, off);
  }
  __shared__ float red[4][3];
  if ((t & 63) == 0) {
    red[t >> 6][0] = p0; red[t >> 6][1] = p1; red[t >> 6][2] = p2;
  }
  __syncthreads();
  if (t < 3) out[b * 3 + t] = b3[t] + red[0][t] + red[1][t] + red[2][t] + red[3][t];
}

extern "C" void kernel_launch(void* const* d_in, const int* in_sizes, int n_in,
                              void* d_out, int out_size, void* d_ws, size_t ws_size,
                              hipStream_t stream) {
  (void)in_sizes; (void)n_in; (void)out_size; (void)ws_size;
  const float* P   = (const float*)d_in[0];
  const float* H   = (const float*)d_in[1];
  const float* W_F = (const float*)d_in[2];
  const float* W_G = (const float*)d_in[3];
  const float* W1  = (const float*)d_in[4];
  const float* b1  = (const float*)d_in[5];
  const float* W2  = (const float*)d_in[6];
  const float* b2  = (const float*)d_in[7];
  const float* W3  = (const float*)d_in[8];
  const float* b3  = (const float*)d_in[9];
  float* out = (float*)d_out;

  char* wsp = (char*)d_ws;
  auto alloc = [&](size_t bytes) {
    char* p = wsp;
    wsp += (bytes + 255) & ~(size_t)255;
    return p;
  };
  short*    Pp_h  = (short*)alloc(16384ull * 1024 * 2);     // [P;H] split planes
  short*    Pp_l  = (short*)alloc(16384ull * 1024 * 2);
  _Float16* Cat16 = (_Float16*)alloc(16384ull * 2048 * 2);  // [P|betas ; H|alphas]
  short*    Fbuf  = (short*)alloc(32ull * 1024 * 1024 * 2); // 64 MB: F planes
  _Float16* PHbT  = (_Float16*)alloc(64ull * 1024 * 256 * 2); // 32 MB: P^T|H^T fp16
  short*    WFT_h = (short*)alloc(1024ull * 1024 * 2);
  short*    WFT_l = (short*)alloc(1024ull * 1024 * 2);
  _Float16* WGT16 = (_Float16*)alloc(2048ull * 2048 * 2);
  float*    eijs  = (float*)alloc(32ull * 256 * 256 * 4);
  _Float16* attn  = (_Float16*)alloc(32ull * 256 * 256 * 2);  // 4 MB exactly
  _Float16* attnT = (_Float16*)alloc(32ull * 256 * 256 * 2);  // adjacent to attn
  float*    agg   = (float*)alloc(32ull * 4096 * 4);
  float*    c1f   = (float*)alloc(32ull * 2048 * 4);
  float*    c2f   = (float*)alloc(32ull * 2048 * 4);
  float*    a1f   = (float*)alloc(32ull * 2048 * 4);

  short* F_h = Fbuf;
  short* F_l = Fbuf + 16384ull * 1024;

  // 1. fused input conversion + per-batch transpose; weight transposes
  conv_in_t<<<dim3(32, 8, 64), 256, 0, stream>>>(P, H, Pp_h, Pp_l, Cat16, PHbT);
  transpose_split<<<dim3(32, 32, 1), 256, 0, stream>>>(W_F, WFT_h, WFT_l, 1024, 1024);
  transpose_f16<<<dim3(64, 64, 1), 256, 0, stream>>>(W_G, WGT16, 2048, 2048);

  // 2. F = tanh([P;H] @ W_F), split bf16x3, split store
  gemm_nt_split<1, 1><<<dim3(128, 8, 1), 256, 0, stream>>>(
      Pp_h, Pp_l, 1024, 0, WFT_h, WFT_l, 1024, 0,
      F_h, F_l, 1024, 0, 16384, 1024, 1);

  // 3. scores E[z] = F_p[z] @ F_h[z]^T, split bf16x3, split-K x2 (atomic fp32)
  zero_f32<<<8192, 256, 0, stream>>>(eijs, 32 * 256 * 256);
  gemm_nt_split<0, 0><<<dim3(2, 2, 64), 256, 0, stream>>>(
      F_h, F_l, 1024, 256 * 1024,
      F_h + 8192ull * 1024, F_l + 8192ull * 1024, 1024, 256 * 1024,
      eijs, nullptr, 256, 65536, 256, 1024, 2);

  // 4. softmax -> fp16 attn; attn^T (adjacent buffer => one fused GEMM later)
  softmax_rows<<<2048, 256, 0, stream>>>(eijs, attn);
  transpose_b2b<<<dim3(8, 8, 32), 256, 0, stream>>>(
      (const short*)attn, (short*)attnT, 256, 256, 65536, 65536);

  // 5. betas (z<32: attn @ H^T-panels) and alphas (z>=32: attn^T @ P^T-panels)
  //    in ONE launch: A spans [attn|attnT], B = PHbT[(z^32)] (z<32 -> H^T,
  //    z>=32 -> P^T), C = Cat right halves (contiguous across z).
  gemm_f16<<<dim3(2, 8, 64), 256, 0, stream>>>(
      attn, 256, 65536, PHbT, 256, 1024 * 256,
      Cat16 + 1024, 2048, 256 * 2048, 256, 32);

  // 6. V = tanh(Cat @ W_G) fused column-sum -> agg
  zero_f32<<<512, 256, 0, stream>>>(agg, 32 * 4096);
  gemm_f16_sum8<<<dim3(64, 8, 1), 512, 0, stream>>>(
      Cat16, 2048, WGT16, 2048, 2048, agg);

  // 7. classifier: fp32 skinny GEMMs straight from W1/W2 (no transposes)
  zero_f32<<<256, 256, 0, stream>>>(c1f, 32 * 2048);
  skinny_gemm<<<dim3(32, 16), 256, 0, stream>>>(agg, W1, c1f, 2048, 4096);
  bias_tanh_f32<<<256, 256, 0, stream>>>(c1f, b1, a1f, 32 * 2048);
  zero_f32<<<256, 256, 0, stream>>>(c2f, 32 * 2048);
  skinny_gemm<<<dim3(32, 8), 256, 0, stream>>>(a1f, W2, c2f, 2048, 2048);
  logits2<<<32, 256, 0, stream>>>(c2f, b2, W3, b3, out);
}

// Round 7
// 595.906 us; speedup vs baseline: 1.0079x; 1.0079x over previous
//
#include <hip/hip_runtime.h>
#include <hip/hip_bf16.h>
#include <stdint.h>

// Shapes: B=32, L=256, D=1024, ALIGN=1024, FF=2048, NC=3
// Precision plan:
//  - F proj (split bf16x3), E scores (split bf16x3): the softmax-sensitive path
//  - attn, betas/alphas: fp16 single, V = tanh(Cat@W_G): fp16 single + colsum
//  - classifier: fp32 VALU skinny GEMM (more accurate than split-bf16x3,
//    and W1/W2 are memory-bound: 0.5 GFLOP vs 48 MB of weights)

typedef __attribute__((ext_vector_type(8))) short    short8_t;   // 8 bf16
typedef __attribute__((ext_vector_type(4))) float    float4_t;
typedef __attribute__((ext_vector_type(8))) _Float16 half8_t;
typedef __attribute__((ext_vector_type(4))) _Float16 half4_t;
typedef __attribute__((ext_vector_type(2))) _Float16 half2_t;

#define DEVI static __device__ __forceinline__

DEVI short f2bf(float f) {
  union { float f; unsigned u; } v; v.f = f;
  unsigned r = v.u + 0x7fffu + ((v.u >> 16) & 1u);   // RNE
  return (short)(r >> 16);
}
DEVI float bf2f(short s) {
  union { unsigned u; float f; } v;
  v.u = ((unsigned)(unsigned short)s) << 16;
  return v.f;
}
DEVI void split2(float x, short& hi, short& lo) {
  hi = f2bf(x);
  lo = f2bf(x - bf2f(hi));
}
DEVI float fast_tanh(float x) {
  float e = __expf(2.0f * x);
  return 1.0f - 2.0f / (e + 1.0f);
}
DEVI void gload16(const void* g, void* l) {
  // async global->LDS, 16B/lane; LDS dest = wave-uniform base + lane*16
  __builtin_amdgcn_global_load_lds(
      (const __attribute__((address_space(1))) void*)g,
      (__attribute__((address_space(3))) void*)l, 16, 0, 0);
}

// ---------------------------------------------------------------------------
// Split-bf16 NT GEMM (A=Ah+Al, B=Bh+Bl), 128x128 tile, BK=32, 4 waves,
// 3 MFMAs per product (hh,hl,lh). blockIdx.z = batch*kslices + kslice.
// OUT_MODE: 0 = fp32 atomicAdd (split-K accumulation; C pre-zeroed)
//           1 = split bf16 store (optional tanh)
// global_load_lds width=16 staging; unpadded [128][32] planes, linear LDS
// dest (row t>>2, slot t&3), pre-swizzled global source chunk (t&3)^((t>>3)&3)
// => slot s of row r holds chunk s^((r>>1)&3); reads at slot q^((m15>>1)&3).
// ---------------------------------------------------------------------------
template <int DO_TANH, int OUT_MODE>
__global__ __launch_bounds__(256) void gemm_nt_split(
    const short* __restrict__ Ah, const short* __restrict__ Al, int lda, long sA,
    const short* __restrict__ Bh, const short* __restrict__ Bl, int ldb, long sB,
    void* __restrict__ Ch, void* __restrict__ Cl, int ldc, long sC,
    int M, int K, int kslices)
{
  __shared__ __align__(16) short Ash[128 * 32];
  __shared__ __align__(16) short Asl[128 * 32];
  __shared__ __align__(16) short Bsh[128 * 32];
  __shared__ __align__(16) short Bsl[128 * 32];

  const int z  = blockIdx.z;
  const int zb = z / kslices;
  const int zk = z - zb * kslices;
  const int Ksub = K / kslices;
  const int kbeg = zk * Ksub, kend = kbeg + Ksub;

  Ah += (size_t)zb * sA;  Al += (size_t)zb * sA;
  Bh += (size_t)zb * sB;  Bl += (size_t)zb * sB;

  const int row0 = blockIdx.x * 128;
  const int col0 = blockIdx.y * 128;

  const int t    = threadIdx.x;
  const int lane = t & 63;
  const int wave = t >> 6;
  const int wr = wave >> 1, wc = wave & 1;
  const int m15 = lane & 15, q = lane >> 4;

  const int schk = ((t & 3) ^ ((t >> 3) & 3)) * 8;
  const short* pAh = Ah + (size_t)(row0 + (t >> 2)) * lda + kbeg + schk;
  const short* pAl = Al + (size_t)(row0 + (t >> 2)) * lda + kbeg + schk;
  const short* pBh = Bh + (size_t)(col0 + (t >> 2)) * ldb + kbeg + schk;
  const short* pBl = Bl + (size_t)(col0 + (t >> 2)) * ldb + kbeg + schk;
  const size_t a64 = (size_t)64 * lda, b64 = (size_t)64 * ldb;
  short* lAh = &Ash[wave * 512];
  short* lAl = &Asl[wave * 512];
  short* lBh = &Bsh[wave * 512];
  short* lBl = &Bsl[wave * 512];

  const int fs2 = (q ^ ((m15 >> 1) & 3)) * 8;

  float4_t acc[4][4];
#pragma unroll
  for (int i = 0; i < 4; ++i)
#pragma unroll
    for (int j = 0; j < 4; ++j) acc[i][j] = (float4_t)0.0f;

  for (int k0 = kbeg; k0 < kend; k0 += 32) {
    gload16(pAh, lAh);  gload16(pAh + a64, lAh + 2048);
    gload16(pAl, lAl);  gload16(pAl + a64, lAl + 2048);
    gload16(pBh, lBh);  gload16(pBh + b64, lBh + 2048);
    gload16(pBl, lBl);  gload16(pBl + b64, lBl + 2048);
    pAh += 32; pAl += 32; pBh += 32; pBl += 32;
    __syncthreads();

    short8_t ah[4], al[4];
#pragma unroll
    for (int i = 0; i < 4; ++i) {
      const int ra = (wr * 64 + i * 16 + m15) * 32 + fs2;
      ah[i] = *(const short8_t*)&Ash[ra];
      al[i] = *(const short8_t*)&Asl[ra];
    }
#pragma unroll
    for (int j = 0; j < 4; ++j) {
      const int rb = (wc * 64 + j * 16 + m15) * 32 + fs2;
      short8_t bh = *(const short8_t*)&Bsh[rb];
      short8_t bl = *(const short8_t*)&Bsl[rb];
#pragma unroll
      for (int i = 0; i < 4; ++i) {
        acc[i][j] = __builtin_amdgcn_mfma_f32_16x16x32_bf16(ah[i], bh, acc[i][j], 0, 0, 0);
        acc[i][j] = __builtin_amdgcn_mfma_f32_16x16x32_bf16(ah[i], bl, acc[i][j], 0, 0, 0);
        acc[i][j] = __builtin_amdgcn_mfma_f32_16x16x32_bf16(al[i], bh, acc[i][j], 0, 0, 0);
      }
    }
    __syncthreads();
  }

  short* Chs = (short*)Ch + (size_t)zb * sC;
  short* Cls = (short*)Cl + (size_t)zb * sC;
  float* Cf  = (float*)Ch + (size_t)zb * sC;
#pragma unroll
  for (int i = 0; i < 4; ++i) {
#pragma unroll
    for (int r = 0; r < 4; ++r) {
      int gm = row0 + wr * 64 + i * 16 + q * 4 + r;
      if (gm < M) {
#pragma unroll
        for (int j = 0; j < 4; ++j) {
          int gn = col0 + wc * 64 + j * 16 + m15;
          float v = acc[i][j][r];
          if (DO_TANH) v = fast_tanh(v);
          if (OUT_MODE == 0) {
            atomicAdd(&Cf[(size_t)gm * ldc + gn], v);
          } else {
            short hi, lo; split2(v, hi, lo);
            Chs[(size_t)gm * ldc + gn] = hi;
            Cls[(size_t)gm * ldc + gn] = lo;
          }
        }
      }
    }
  }
}

// ---------------------------------------------------------------------------
// fp16 single-pass NT GEMM, BK=64, async global_load_lds staging, XOR
// chunk-swizzled unpadded LDS (0 bank conflicts). fp16 store.
// B batch index = z ^ bxor (one launch covers betas (z<32, B=H^T) and
// alphas (z>=32, B=P^T) with PHbT layout [P^T batches | H^T batches]).
// K % 64 == 0.
// ---------------------------------------------------------------------------
__global__ __launch_bounds__(256) void gemm_f16(
    const _Float16* __restrict__ A, int lda, long sA,
    const _Float16* __restrict__ B, int ldb, long sB,
    _Float16* __restrict__ C, int ldc, long sC,
    int K, int bxor)
{
  __shared__ __align__(16) _Float16 As[2 * 128 * 32];
  __shared__ __align__(16) _Float16 Bs[2 * 128 * 32];

  const int z = blockIdx.z;
  A += (size_t)z * sA;
  B += (size_t)(z ^ bxor) * sB;

  const int row0 = blockIdx.x * 128;
  const int col0 = blockIdx.y * 128;
  const int t = threadIdx.x, lane = t & 63, wave = t >> 6;
  const int wr = wave >> 1, wc = wave & 1;
  const int m15 = lane & 15, q = lane >> 4;

  const int srow = wave * 32 + (lane >> 2);
  const int cg   = ((lane & 3) ^ ((lane >> 3) & 3)) * 8;
  const _Float16* gA0 = A + (size_t)(row0 + srow) * lda + cg;
  const _Float16* gA1 = gA0 + (size_t)16 * lda;
  const _Float16* gB0 = B + (size_t)(col0 + srow) * ldb + cg;
  const _Float16* gB1 = gB0 + (size_t)16 * ldb;
  const _Float16* gA0b = gA0 + 32;
  const _Float16* gA1b = gA1 + 32;
  const _Float16* gB0b = gB0 + 32;
  const _Float16* gB1b = gB1 + 32;
  _Float16* lA0  = &As[(wave * 32) * 32];
  _Float16* lA1  = &As[(wave * 32 + 16) * 32];
  _Float16* lB0  = &Bs[(wave * 32) * 32];
  _Float16* lB1  = &Bs[(wave * 32 + 16) * 32];
  _Float16* lA0b = lA0 + 4096;
  _Float16* lA1b = lA1 + 4096;
  _Float16* lB0b = lB0 + 4096;
  _Float16* lB1b = lB1 + 4096;

  const int fs = (q ^ ((m15 >> 1) & 3)) * 8;
  int aoff[4], boff[4];
#pragma unroll
  for (int i = 0; i < 4; ++i) {
    aoff[i] = (wr * 64 + i * 16 + m15) * 32 + fs;
    boff[i] = (wc * 64 + i * 16 + m15) * 32 + fs;
  }

  float4_t acc[4][4];
#pragma unroll
  for (int i = 0; i < 4; ++i)
#pragma unroll
    for (int j = 0; j < 4; ++j) acc[i][j] = (float4_t)0.0f;

  for (int k0 = 0; k0 < K; k0 += 64) {
    gload16(gA0, lA0);  gload16(gA1, lA1);
    gload16(gB0, lB0);  gload16(gB1, lB1);
    gload16(gA0b, lA0b); gload16(gA1b, lA1b);
    gload16(gB0b, lB0b); gload16(gB1b, lB1b);
    gA0 += 64; gA1 += 64; gB0 += 64; gB1 += 64;
    gA0b += 64; gA1b += 64; gB0b += 64; gB1b += 64;
    __syncthreads();

#pragma unroll
    for (int h = 0; h < 2; ++h) {
      half8_t af[4], bfr[4];
#pragma unroll
      for (int i = 0; i < 4; ++i) af[i]  = *(const half8_t*)&As[h * 4096 + aoff[i]];
#pragma unroll
      for (int j = 0; j < 4; ++j) bfr[j] = *(const half8_t*)&Bs[h * 4096 + boff[j]];
#pragma unroll
      for (int i = 0; i < 4; ++i)
#pragma unroll
        for (int j = 0; j < 4; ++j)
          acc[i][j] = __builtin_amdgcn_mfma_f32_16x16x32_f16(af[i], bfr[j], acc[i][j], 0, 0, 0);
    }
    __syncthreads();
  }

  {
    _Float16* Cp = C + (size_t)z * sC;
#pragma unroll
    for (int i = 0; i < 4; ++i)
#pragma unroll
      for (int r = 0; r < 4; ++r) {
        int gm = row0 + wr * 64 + i * 16 + q * 4 + r;
#pragma unroll
        for (int j = 0; j < 4; ++j) {
          int gn = col0 + wc * 64 + j * 16 + m15;
          Cp[(size_t)gm * ldc + gn] = (_Float16)acc[i][j][r];
        }
      }
  }
}

// ---------------------------------------------------------------------------
// V-GEMM: fp16 NT, 256x256 tile, BK=32, 512 threads = 8 waves (2M x 4N),
// 4-deep LDS ring (4 x 32 KiB), tile t+2 staged during tile t, ONE barrier
// per K-tile, counted vmcnt(4). Conflict-free chunk swizzle (0 measured).
// Fused tanh + column-sum epilogue -> agg. (Unchanged — at plain-HIP
// template ceiling for this shape class; 143 us / 44% MfmaUtil measured.)
// ---------------------------------------------------------------------------
__global__ __launch_bounds__(512, 2) void gemm_f16_sum8(
    const _Float16* __restrict__ A, int lda,
    const _Float16* __restrict__ B, int ldb,
    int K, float* __restrict__ agg)
{
  __shared__ __align__(16) _Float16 LDS[4][2 * 256 * 32];

  const int row0 = blockIdx.x * 256;
  const int col0 = blockIdx.y * 256;
  const int tid  = threadIdx.x;
  const int lane = tid & 63, wave = tid >> 6;
  const int wr = wave >> 2, wc = wave & 3;     // 2 M-waves x 4 N-waves
  const int m15 = lane & 15, q = lane >> 4;
  const int nt = K / 32;

  const int srow = wave * 32 + (lane >> 2);
  const int cg   = ((lane & 3) ^ ((lane >> 3) & 3)) * 8;
  const _Float16* gA = A + (size_t)(row0 + srow) * lda + cg;
  const _Float16* gB = B + (size_t)(col0 + srow) * ldb + cg;

  auto stageA = [&](int t) {
    const _Float16* g = gA + t * 32;
    _Float16* l = &LDS[t & 3][wave * 1024];
    gload16(g, l);
    gload16(g + (size_t)16 * lda, l + 512);
  };
  auto stageB = [&](int t) {
    const _Float16* g = gB + t * 32;
    _Float16* l = &LDS[t & 3][8192 + wave * 1024];
    gload16(g, l);
    gload16(g + (size_t)16 * ldb, l + 512);
  };

  const int xq = (q ^ ((m15 >> 1) & 3)) * 8;
  int aoff[8], boff[4];
#pragma unroll
  for (int i = 0; i < 8; ++i)
    aoff[i] = (wr * 128 + i * 16 + m15) * 32 + xq;
#pragma unroll
  for (int j = 0; j < 4; ++j)
    boff[j] = 8192 + (wc * 64 + j * 16 + m15) * 32 + xq;

  float4_t acc[8][4];
#pragma unroll
  for (int i = 0; i < 8; ++i)
#pragma unroll
    for (int j = 0; j < 4; ++j) acc[i][j] = (float4_t)0.0f;

  stageA(0); stageB(0);
  stageA(1); stageB(1);
  asm volatile("s_waitcnt vmcnt(4)");
  __builtin_amdgcn_s_barrier();

  for (int t = 0; t < nt; ++t) {
    const _Float16* buf = &LDS[t & 3][0];
    __builtin_amdgcn_sched_barrier(0);

    half8_t a0[4], a1[4], bb[4];
#pragma unroll
    for (int i = 0; i < 4; ++i) a0[i] = *(const half8_t*)&buf[aoff[i]];
#pragma unroll
    for (int j = 0; j < 4; ++j) bb[j] = *(const half8_t*)&buf[boff[j]];
#pragma unroll
    for (int i = 0; i < 4; ++i) a1[i] = *(const half8_t*)&buf[aoff[4 + i]];

    if (t + 2 < nt) { stageA(t + 2); stageB(t + 2); }

    __builtin_amdgcn_s_setprio(1);
#pragma unroll
    for (int i = 0; i < 4; ++i)
#pragma unroll
      for (int j = 0; j < 4; ++j)
        acc[i][j] = __builtin_amdgcn_mfma_f32_16x16x32_f16(a0[i], bb[j], acc[i][j], 0, 0, 0);
#pragma unroll
    for (int i = 0; i < 4; ++i)
#pragma unroll
      for (int j = 0; j < 4; ++j)
        acc[4 + i][j] = __builtin_amdgcn_mfma_f32_16x16x32_f16(a1[i], bb[j], acc[4 + i][j], 0, 0, 0);
    __builtin_amdgcn_s_setprio(0);

    __builtin_amdgcn_sched_barrier(0);
    if (t + 2 < nt) {
      asm volatile("s_waitcnt vmcnt(4)");
    } else if (t + 1 < nt) {
      asm volatile("s_waitcnt vmcnt(0)");
    }
    __builtin_amdgcn_s_barrier();
  }

  // ---- epilogue: tanh + column-sum -> agg[b][half*2048 + col] ----
  const int half_ = row0 >= 8192;
  const int b     = (row0 & 8191) >> 8;
#pragma unroll
  for (int j = 0; j < 4; ++j) {
    float s = 0.0f;
#pragma unroll
    for (int i = 0; i < 8; ++i)
#pragma unroll
      for (int r = 0; r < 4; ++r) s += fast_tanh(acc[i][j][r]);
    s += __shfl_xor(s, 16);
    s += __shfl_xor(s, 32);
    if (q == 0) {
      int col = col0 + wc * 64 + j * 16 + m15;
      atomicAdd(&agg[(size_t)b * 4096 + half_ * 2048 + col], s);
    }
  }
}

// --- fp32 -> split bf16 transpose: out[c][r] (used for W_F) ---
__global__ __launch_bounds__(256) void transpose_split(
    const float* __restrict__ in, short* __restrict__ oh, short* __restrict__ ol,
    int R, int C)
{
  __shared__ float tile[32][33];
  const int tx = threadIdx.x & 31, ty = threadIdx.x >> 5;
  const int c0 = blockIdx.x * 32, r0 = blockIdx.y * 32;
#pragma unroll
  for (int i = 0; i < 4; ++i) {
    int r = ty + i * 8;
    tile[r][tx] = in[(size_t)(r0 + r) * C + c0 + tx];
  }
  __syncthreads();
#pragma unroll
  for (int i = 0; i < 4; ++i) {
    int cc = ty + i * 8;
    float v = tile[tx][cc];
    short hi, lo; split2(v, hi, lo);
    size_t o = (size_t)(c0 + cc) * R + r0 + tx;
    oh[o] = hi;
    ol[o] = lo;
  }
}

// --- fp32 -> fp16 transpose: out[c][r] (used for W_G) ---
__global__ __launch_bounds__(256) void transpose_f16(
    const float* __restrict__ in, _Float16* __restrict__ out, int R, int C)
{
  __shared__ float tile[32][33];
  const int tx = threadIdx.x & 31, ty = threadIdx.x >> 5;
  const int c0 = blockIdx.x * 32, r0 = blockIdx.y * 32;
#pragma unroll
  for (int i = 0; i < 4; ++i) {
    int r = ty + i * 8;
    tile[r][tx] = in[(size_t)(r0 + r) * C + c0 + tx];
  }
  __syncthreads();
#pragma unroll
  for (int i = 0; i < 4; ++i) {
    int cc = ty + i * 8;
    out[(size_t)(c0 + cc) * R + r0 + tx] = (_Float16)tile[tx][cc];
  }
}

// --- fp16 [256x256] batched transpose (attn -> attnT) ---
__global__ __launch_bounds__(256) void transpose_b2b(
    const short* __restrict__ in, short* __restrict__ out,
    int R, int C, long sIn, long sOut)
{
  __shared__ short tile[32][33];
  in  += (size_t)blockIdx.z * sIn;
  out += (size_t)blockIdx.z * sOut;
  const int tx = threadIdx.x & 31, ty = threadIdx.x >> 5;
  const int c0 = blockIdx.x * 32, r0 = blockIdx.y * 32;
#pragma unroll
  for (int i = 0; i < 4; ++i) {
    int r = ty + i * 8;
    tile[r][tx] = in[(size_t)(r0 + r) * C + c0 + tx];
  }
  __syncthreads();
#pragma unroll
  for (int i = 0; i < 4; ++i) {
    int cc = ty + i * 8;
    out[(size_t)(c0 + cc) * R + r0 + tx] = tile[tx][cc];
  }
}

// ---------------------------------------------------------------------------
// Fused input conversion + transpose, VECTORIZED (round-7; round-6 version
// was scalar — G13 violation on a 192 MB-traffic kernel). One pass over P/H
// producing (a) split bf16 planes, (b) fp16 Cat left half, (c) fp16 per-batch
// transpose PHbT[z][1024][256] (z<32 = P^T, z>=32 = H^T).
// grid (16, 4, 64): x = 64-col tile over 1024, y = 64-row tile over 256,
// z = batch. float4 loads (16B/lane), short4/half4 conversion stores,
// half2 transpose writes (32 lanes x 4B = 128B contiguous per col).
// ---------------------------------------------------------------------------
__global__ __launch_bounds__(256) void conv_in_t(
    const float* __restrict__ P, const float* __restrict__ Hh,
    short* __restrict__ oh, short* __restrict__ ol,
    _Float16* __restrict__ cat, _Float16* __restrict__ phbt)
{
  __shared__ __align__(16) float tile[64][68];   // 272B rows, 16B-aligned
  const int zb   = blockIdx.z;
  const int half = zb >> 5, b = zb & 31;
  const float* in = (half ? Hh : P) + (size_t)b * 256 * 1024;
  const int c0 = blockIdx.x * 64;   // col in [0,1024)
  const int r0 = blockIdx.y * 64;   // row in [0,256)
  const int t  = threadIdx.x;
  const int rl = t >> 4;            // 0..15
  const int c4 = (t & 15) * 4;      // 0,4,...,60
  const size_t rowbase = (size_t)half * 8192 + (size_t)b * 256;
#pragma unroll
  for (int i = 0; i < 4; ++i) {
    int r = rl + i * 16;
    float4 v = *(const float4*)&in[(size_t)(r0 + r) * 1024 + c0 + c4];
    *(float4*)&tile[r][c4] = v;
    short4 h, l;
    split2(v.x, h.x, l.x); split2(v.y, h.y, l.y);
    split2(v.z, h.z, l.z); split2(v.w, h.w, l.w);
    size_t o = (rowbase + r0 + r) * 1024 + c0 + c4;
    *(short4*)&oh[o] = h;
    *(short4*)&ol[o] = l;
    half4_t c16;
    c16.x = (_Float16)v.x; c16.y = (_Float16)v.y;
    c16.z = (_Float16)v.z; c16.w = (_Float16)v.w;
    *(half4_t*)&cat[(rowbase + r0 + r) * 2048 + c0 + c4] = c16;
  }
  __syncthreads();
  _Float16* op = phbt + (size_t)zb * 1024 * 256;
  const int tx = t & 31;            // row-pair index: rows 2tx, 2tx+1
  const int w  = t >> 5;            // 0..7
#pragma unroll
  for (int i = 0; i < 8; ++i) {
    int cc = w + i * 8;             // 0..63
    half2_t p;
    p.x = (_Float16)tile[tx * 2][cc];
    p.y = (_Float16)tile[tx * 2 + 1][cc];
    *(half2_t*)&op[(size_t)(c0 + cc) * 256 + r0 + tx * 2] = p;
  }
}

__global__ __launch_bounds__(256) void zero_f32(float* __restrict__ p, int n)
{
  int i = blockIdx.x * 256 + threadIdx.x;
  if (i < n) p[i] = 0.0f;
}

// --- softmax over rows of 256 (one wave per row), fp32 -> fp16 ---
__global__ __launch_bounds__(256) void softmax_rows(
    const float* __restrict__ e, _Float16* __restrict__ attn)
{
  const int row  = blockIdx.x * 4 + (threadIdx.x >> 6);
  const int lane = threadIdx.x & 63;
  const float4 v = *(const float4*)&e[(size_t)row * 256 + lane * 4];
  float m = fmaxf(fmaxf(v.x, v.y), fmaxf(v.z, v.w));
#pragma unroll
  for (int off = 32; off; off >>= 1) m = fmaxf(m, __shfl_xor(m, off));
  float e0 = __expf(v.x - m), e1 = __expf(v.y - m);
  float e2 = __expf(v.z - m), e3 = __expf(v.w - m);
  float s = e0 + e1 + e2 + e3;
#pragma unroll
  for (int off = 32; off; off >>= 1) s += __shfl_xor(s, off);
  float inv = 1.0f / s;
  half4_t o;
  o.x = (_Float16)(e0 * inv); o.y = (_Float16)(e1 * inv);
  o.z = (_Float16)(e2 * inv); o.w = (_Float16)(e3 * inv);
  *(half4_t*)&attn[(size_t)row * 256 + lane * 4] = o;
}

// ---------------------------------------------------------------------------
// Skinny fp32 GEMM: out[32][N] += A[32][K-slice] @ B[K-slice][N], atomic out.
// grid (N/64, K/256); block 256. A-slice stored TRANSPOSED in LDS [k][m]
// (+1 pad: conflict-free writes; reads are wave-uniform broadcasts).
// Wave w owns rows w*8..w*8+7, lane l owns col n0+l; B rows coalesced.
// ---------------------------------------------------------------------------
__global__ __launch_bounds__(256) void skinny_gemm(
    const float* __restrict__ A, const float* __restrict__ B,
    float* __restrict__ out, int N, int K)
{
  __shared__ float Asl[256][33];
  const int n0 = blockIdx.x * 64;
  const int k0 = blockIdx.y * 256;
  const int t  = threadIdx.x;
#pragma unroll
  for (int j = 0; j < 32; ++j) {
    // coalesced A read (k fast), padded-transposed LDS write (conflict-free)
    Asl[t][j] = A[(size_t)j * K + k0 + t];
  }
  __syncthreads();
  const int l = t & 63, w = t >> 6;
  const int n = n0 + l;
  float acc[8] = {0.f, 0.f, 0.f, 0.f, 0.f, 0.f, 0.f, 0.f};
  const float* Bp = B + (size_t)k0 * N + n;
#pragma unroll 4
  for (int k = 0; k < 256; ++k) {
    float bv = Bp[(size_t)k * N];
#pragma unroll
    for (int m = 0; m < 8; ++m)
      acc[m] += Asl[k][w * 8 + m] * bv;
  }
#pragma unroll
  for (int m = 0; m < 8; ++m)
    atomicAdd(&out[(size_t)(w * 8 + m) * N + n], acc[m]);
}

// --- a1 = tanh(c + bias), fp32 out ---
__global__ __launch_bounds__(256) void bias_tanh_f32(
    const float* __restrict__ c, const float* __restrict__ bias,
    float* __restrict__ o, int n)
{
  int i = blockIdx.x * 256 + threadIdx.x;
  if (i < n) o[i] = fast_tanh(c[i] + bias[i & 2047]);
}

// --- logits: block b: out[b][0..2] = tanh(c2f[b]+b2) @ W3 + b3 ---
__global__ __launch_bounds__(256) void logits2(
    const float* __restrict__ c2f, const float* __restrict__ b2,
    const float* __restrict__ W3, const float* __restrict__ b3,
    float* __restrict__ out)
{
  const int b = blockIdx.x, t = threadIdx.x;
  float p0 = 0.f, p1 = 0.f, p2 = 0.f;
  for (int k = t; k < 2048; k += 256) {
    float a = fast_tanh(c2f[b * 2048 + k] + b2[k]);
    p0 += a * W3[k * 3 + 0];
    p1 += a * W3[k * 3 + 1];
    p2 += a * W3[k * 3 + 2];
  }
#pragma unroll
  for (int off = 32; off; off >>= 1) {
    p0 += __shfl_xor(p0, off);
    p1 += __shfl_xor(p1, off);
    p2 += __shfl_xor(p2, off);
  }
  __shared__ float red[4][3];
  if ((t & 63) == 0) {
    red[t >> 6][0] = p0; red[t >> 6][1] = p1; red[t >> 6][2] = p2;
  }
  __syncthreads();
  if (t < 3) out[b * 3 + t] = b3[t] + red[0][t] + red[1][t] + red[2][t] + red[3][t];
}

extern "C" void kernel_launch(void* const* d_in, const int* in_sizes, int n_in,
                              void* d_out, int out_size, void* d_ws, size_t ws_size,
                              hipStream_t stream) {
  (void)in_sizes; (void)n_in; (void)out_size; (void)ws_size;
  const float* P   = (const float*)d_in[0];
  const float* H   = (const float*)d_in[1];
  const float* W_F = (const float*)d_in[2];
  const float* W_G = (const float*)d_in[3];
  const float* W1  = (const float*)d_in[4];
  const float* b1  = (const float*)d_in[5];
  const float* W2  = (const float*)d_in[6];
  const float* b2  = (const float*)d_in[7];
  const float* W3  = (const float*)d_in[8];
  const float* b3  = (const float*)d_in[9];
  float* out = (float*)d_out;

  char* wsp = (char*)d_ws;
  auto alloc = [&](size_t bytes) {
    char* p = wsp;
    wsp += (bytes + 255) & ~(size_t)255;
    return p;
  };
  short*    Pp_h  = (short*)alloc(16384ull * 1024 * 2);     // [P;H] split planes
  short*    Pp_l  = (short*)alloc(16384ull * 1024 * 2);
  _Float16* Cat16 = (_Float16*)alloc(16384ull * 2048 * 2);  // [P|betas ; H|alphas]
  short*    Fbuf  = (short*)alloc(32ull * 1024 * 1024 * 2); // 64 MB: F planes
  _Float16* PHbT  = (_Float16*)alloc(64ull * 1024 * 256 * 2); // 32 MB: P^T|H^T fp16
  short*    WFT_h = (short*)alloc(1024ull * 1024 * 2);
  short*    WFT_l = (short*)alloc(1024ull * 1024 * 2);
  _Float16* WGT16 = (_Float16*)alloc(2048ull * 2048 * 2);
  float*    eijs  = (float*)alloc(32ull * 256 * 256 * 4);
  _Float16* attn  = (_Float16*)alloc(32ull * 256 * 256 * 2);  // 4 MB exactly
  _Float16* attnT = (_Float16*)alloc(32ull * 256 * 256 * 2);  // adjacent to attn
  float*    agg   = (float*)alloc(32ull * 4096 * 4);
  float*    c1f   = (float*)alloc(32ull * 2048 * 4);
  float*    c2f   = (float*)alloc(32ull * 2048 * 4);
  float*    a1f   = (float*)alloc(32ull * 2048 * 4);

  short* F_h = Fbuf;
  short* F_l = Fbuf + 16384ull * 1024;

  // 1. fused input conversion + per-batch transpose (vectorized); weight transposes
  conv_in_t<<<dim3(16, 4, 64), 256, 0, stream>>>(P, H, Pp_h, Pp_l, Cat16, PHbT);
  transpose_split<<<dim3(32, 32, 1), 256, 0, stream>>>(W_F, WFT_h, WFT_l, 1024, 1024);
  transpose_f16<<<dim3(64, 64, 1), 256, 0, stream>>>(W_G, WGT16, 2048, 2048);

  // 2. F = tanh([P;H] @ W_F), split bf16x3, split store
  gemm_nt_split<1, 1><<<dim3(128, 8, 1), 256, 0, stream>>>(
      Pp_h, Pp_l, 1024, 0, WFT_h, WFT_l, 1024, 0,
      F_h, F_l, 1024, 0, 16384, 1024, 1);

  // 3. scores E[z] = F_p[z] @ F_h[z]^T, split bf16x3, split-K x4 (atomic fp32)
  //    (kslices=4 restored: 512 blocks = 2/CU; round-6's kslices=2 left
  //     1 block/CU -> no cross-block cover for the barrier drain)
  zero_f32<<<8192, 256, 0, stream>>>(eijs, 32 * 256 * 256);
  gemm_nt_split<0, 0><<<dim3(2, 2, 128), 256, 0, stream>>>(
      F_h, F_l, 1024, 256 * 1024,
      F_h + 8192ull * 1024, F_l + 8192ull * 1024, 1024, 256 * 1024,
      eijs, nullptr, 256, 65536, 256, 1024, 4);

  // 4. softmax -> fp16 attn; attn^T
  softmax_rows<<<2048, 256, 0, stream>>>(eijs, attn);
  transpose_b2b<<<dim3(8, 8, 32), 256, 0, stream>>>(
      (const short*)attn, (short*)attnT, 256, 256, 65536, 65536);

  // 5. betas (z<32) and alphas (z>=32) in ONE launch
  gemm_f16<<<dim3(2, 8, 64), 256, 0, stream>>>(
      attn, 256, 65536, PHbT, 256, 1024 * 256,
      Cat16 + 1024, 2048, 256 * 2048, 256, 32);

  // 6. V = tanh(Cat @ W_G) fused column-sum -> agg
  zero_f32<<<512, 256, 0, stream>>>(agg, 32 * 4096);
  gemm_f16_sum8<<<dim3(64, 8, 1), 512, 0, stream>>>(
      Cat16, 2048, WGT16, 2048, 2048, agg);

  // 7. classifier: fp32 skinny GEMMs straight from W1/W2 (no transposes)
  zero_f32<<<256, 256, 0, stream>>>(c1f, 32 * 2048);
  skinny_gemm<<<dim3(32, 16), 256, 0, stream>>>(agg, W1, c1f, 2048, 4096);
  bias_tanh_f32<<<256, 256, 0, stream>>>(c1f, b1, a1f, 32 * 2048);
  zero_f32<<<256, 256, 0, stream>>>(c2f, 32 * 2048);
  skinny_gemm<<<dim3(32, 8), 256, 0, stream>>>(a1f, W2, c2f, 2048, 2048);
  logits2<<<32, 256, 0, stream>>>(c2f, b2, W3, b3, out);
}

// Round 8
// 560.382 us; speedup vs baseline: 1.0718x; 1.0634x over previous
//
#include <hip/hip_runtime.h>
#include <hip/hip_bf16.h>
#include <stdint.h>

// Shapes: B=32, L=256, D=1024, ALIGN=1024, FF=2048, NC=3
// Precision plan:
//  - F proj (split bf16x3), E scores (split bf16x3): the softmax-sensitive path
//  - attn, betas/alphas: fp16 single, V = tanh(Cat@W_G): fp16 single + colsum
//  - classifier: fp32 VALU skinny GEMM
// Graph plan (round 8): 12 launches, no fp32 atomics outside sum8's agg.
//  E split-K and classifier split-K use per-slice panels + consumer-side sum.

typedef __attribute__((ext_vector_type(8))) short    short8_t;   // 8 bf16
typedef __attribute__((ext_vector_type(4))) float    float4_t;
typedef __attribute__((ext_vector_type(8))) _Float16 half8_t;
typedef __attribute__((ext_vector_type(4))) _Float16 half4_t;
typedef __attribute__((ext_vector_type(2))) _Float16 half2_t;

#define DEVI static __device__ __forceinline__

DEVI short f2bf(float f) {
  union { float f; unsigned u; } v; v.f = f;
  unsigned r = v.u + 0x7fffu + ((v.u >> 16) & 1u);   // RNE
  return (short)(r >> 16);
}
DEVI float bf2f(short s) {
  union { unsigned u; float f; } v;
  v.u = ((unsigned)(unsigned short)s) << 16;
  return v.f;
}
DEVI void split2(float x, short& hi, short& lo) {
  hi = f2bf(x);
  lo = f2bf(x - bf2f(hi));
}
DEVI float fast_tanh(float x) {
  float e = __expf(2.0f * x);
  return 1.0f - 2.0f / (e + 1.0f);
}
DEVI void gload16(const void* g, void* l) {
  // async global->LDS, 16B/lane; LDS dest = wave-uniform base + lane*16
  __builtin_amdgcn_global_load_lds(
      (const __attribute__((address_space(1))) void*)g,
      (__attribute__((address_space(3))) void*)l, 16, 0, 0);
}

// ---------------------------------------------------------------------------
// Split-bf16 NT GEMM (A=Ah+Al, B=Bh+Bl), 128x128 tile, BK=32, 4 waves,
// 3 MFMAs per product (hh,hl,lh). blockIdx.z = batch*kslices + kslice.
// OUT_MODE: 1 = split bf16 store (optional tanh), C panel index zb
//           2 = plain fp32 store, C panel index z (per-slice split-K panels;
//               consumer sums the kslices — no atomics, no pre-zero)
// global_load_lds width=16 staging; unpadded [128][32] planes, linear LDS
// dest (row t>>2, slot t&3), pre-swizzled global source chunk (t&3)^((t>>3)&3)
// => slot s of row r holds chunk s^((r>>1)&3); reads at slot q^((m15>>1)&3).
// ---------------------------------------------------------------------------
template <int DO_TANH, int OUT_MODE>
__global__ __launch_bounds__(256) void gemm_nt_split(
    const short* __restrict__ Ah, const short* __restrict__ Al, int lda, long sA,
    const short* __restrict__ Bh, const short* __restrict__ Bl, int ldb, long sB,
    void* __restrict__ Ch, void* __restrict__ Cl, int ldc, long sC,
    int M, int K, int kslices)
{
  __shared__ __align__(16) short Ash[128 * 32];
  __shared__ __align__(16) short Asl[128 * 32];
  __shared__ __align__(16) short Bsh[128 * 32];
  __shared__ __align__(16) short Bsl[128 * 32];

  const int z  = blockIdx.z;
  const int zb = z / kslices;
  const int Ksub = K / kslices;
  const int zk = z - zb * kslices;
  const int kbeg = zk * Ksub, kend = kbeg + Ksub;

  Ah += (size_t)zb * sA;  Al += (size_t)zb * sA;
  Bh += (size_t)zb * sB;  Bl += (size_t)zb * sB;

  const int row0 = blockIdx.x * 128;
  const int col0 = blockIdx.y * 128;

  const int t    = threadIdx.x;
  const int lane = t & 63;
  const int wave = t >> 6;
  const int wr = wave >> 1, wc = wave & 1;
  const int m15 = lane & 15, q = lane >> 4;

  const int schk = ((t & 3) ^ ((t >> 3) & 3)) * 8;
  const short* pAh = Ah + (size_t)(row0 + (t >> 2)) * lda + kbeg + schk;
  const short* pAl = Al + (size_t)(row0 + (t >> 2)) * lda + kbeg + schk;
  const short* pBh = Bh + (size_t)(col0 + (t >> 2)) * ldb + kbeg + schk;
  const short* pBl = Bl + (size_t)(col0 + (t >> 2)) * ldb + kbeg + schk;
  const size_t a64 = (size_t)64 * lda, b64 = (size_t)64 * ldb;
  short* lAh = &Ash[wave * 512];
  short* lAl = &Asl[wave * 512];
  short* lBh = &Bsh[wave * 512];
  short* lBl = &Bsl[wave * 512];

  const int fs2 = (q ^ ((m15 >> 1) & 3)) * 8;

  float4_t acc[4][4];
#pragma unroll
  for (int i = 0; i < 4; ++i)
#pragma unroll
    for (int j = 0; j < 4; ++j) acc[i][j] = (float4_t)0.0f;

  for (int k0 = kbeg; k0 < kend; k0 += 32) {
    gload16(pAh, lAh);  gload16(pAh + a64, lAh + 2048);
    gload16(pAl, lAl);  gload16(pAl + a64, lAl + 2048);
    gload16(pBh, lBh);  gload16(pBh + b64, lBh + 2048);
    gload16(pBl, lBl);  gload16(pBl + b64, lBl + 2048);
    pAh += 32; pAl += 32; pBh += 32; pBl += 32;
    __syncthreads();

    short8_t ah[4], al[4];
#pragma unroll
    for (int i = 0; i < 4; ++i) {
      const int ra = (wr * 64 + i * 16 + m15) * 32 + fs2;
      ah[i] = *(const short8_t*)&Ash[ra];
      al[i] = *(const short8_t*)&Asl[ra];
    }
#pragma unroll
    for (int j = 0; j < 4; ++j) {
      const int rb = (wc * 64 + j * 16 + m15) * 32 + fs2;
      short8_t bh = *(const short8_t*)&Bsh[rb];
      short8_t bl = *(const short8_t*)&Bsl[rb];
#pragma unroll
      for (int i = 0; i < 4; ++i) {
        acc[i][j] = __builtin_amdgcn_mfma_f32_16x16x32_bf16(ah[i], bh, acc[i][j], 0, 0, 0);
        acc[i][j] = __builtin_amdgcn_mfma_f32_16x16x32_bf16(ah[i], bl, acc[i][j], 0, 0, 0);
        acc[i][j] = __builtin_amdgcn_mfma_f32_16x16x32_bf16(al[i], bh, acc[i][j], 0, 0, 0);
      }
    }
    __syncthreads();
  }

  short* Chs = (short*)Ch + (size_t)zb * sC;
  short* Cls = (short*)Cl + (size_t)zb * sC;
  float* Cf  = (float*)Ch + (size_t)(OUT_MODE == 2 ? z : zb) * sC;
#pragma unroll
  for (int i = 0; i < 4; ++i) {
#pragma unroll
    for (int r = 0; r < 4; ++r) {
      int gm = row0 + wr * 64 + i * 16 + q * 4 + r;
      if (gm < M) {
#pragma unroll
        for (int j = 0; j < 4; ++j) {
          int gn = col0 + wc * 64 + j * 16 + m15;
          float v = acc[i][j][r];
          if (DO_TANH) v = fast_tanh(v);
          if (OUT_MODE == 2) {
            Cf[(size_t)gm * ldc + gn] = v;
          } else {
            short hi, lo; split2(v, hi, lo);
            Chs[(size_t)gm * ldc + gn] = hi;
            Cls[(size_t)gm * ldc + gn] = lo;
          }
        }
      }
    }
  }
}

// ---------------------------------------------------------------------------
// fp16 single-pass NT GEMM, BK=64, async global_load_lds staging, XOR
// chunk-swizzled unpadded LDS (0 bank conflicts). fp16 store.
// B batch index = z ^ bxor (one launch covers betas (z<32, B=H^T) and
// alphas (z>=32, B=P^T) with PHbT layout [P^T batches | H^T batches]).
// K % 64 == 0.
// ---------------------------------------------------------------------------
__global__ __launch_bounds__(256) void gemm_f16(
    const _Float16* __restrict__ A, int lda, long sA,
    const _Float16* __restrict__ B, int ldb, long sB,
    _Float16* __restrict__ C, int ldc, long sC,
    int K, int bxor)
{
  __shared__ __align__(16) _Float16 As[2 * 128 * 32];
  __shared__ __align__(16) _Float16 Bs[2 * 128 * 32];

  const int z = blockIdx.z;
  A += (size_t)z * sA;
  B += (size_t)(z ^ bxor) * sB;

  const int row0 = blockIdx.x * 128;
  const int col0 = blockIdx.y * 128;
  const int t = threadIdx.x, lane = t & 63, wave = t >> 6;
  const int wr = wave >> 1, wc = wave & 1;
  const int m15 = lane & 15, q = lane >> 4;

  const int srow = wave * 32 + (lane >> 2);
  const int cg   = ((lane & 3) ^ ((lane >> 3) & 3)) * 8;
  const _Float16* gA0 = A + (size_t)(row0 + srow) * lda + cg;
  const _Float16* gA1 = gA0 + (size_t)16 * lda;
  const _Float16* gB0 = B + (size_t)(col0 + srow) * ldb + cg;
  const _Float16* gB1 = gB0 + (size_t)16 * ldb;
  const _Float16* gA0b = gA0 + 32;
  const _Float16* gA1b = gA1 + 32;
  const _Float16* gB0b = gB0 + 32;
  const _Float16* gB1b = gB1 + 32;
  _Float16* lA0  = &As[(wave * 32) * 32];
  _Float16* lA1  = &As[(wave * 32 + 16) * 32];
  _Float16* lB0  = &Bs[(wave * 32) * 32];
  _Float16* lB1  = &Bs[(wave * 32 + 16) * 32];
  _Float16* lA0b = lA0 + 4096;
  _Float16* lA1b = lA1 + 4096;
  _Float16* lB0b = lB0 + 4096;
  _Float16* lB1b = lB1 + 4096;

  const int fs = (q ^ ((m15 >> 1) & 3)) * 8;
  int aoff[4], boff[4];
#pragma unroll
  for (int i = 0; i < 4; ++i) {
    aoff[i] = (wr * 64 + i * 16 + m15) * 32 + fs;
    boff[i] = (wc * 64 + i * 16 + m15) * 32 + fs;
  }

  float4_t acc[4][4];
#pragma unroll
  for (int i = 0; i < 4; ++i)
#pragma unroll
    for (int j = 0; j < 4; ++j) acc[i][j] = (float4_t)0.0f;

  for (int k0 = 0; k0 < K; k0 += 64) {
    gload16(gA0, lA0);  gload16(gA1, lA1);
    gload16(gB0, lB0);  gload16(gB1, lB1);
    gload16(gA0b, lA0b); gload16(gA1b, lA1b);
    gload16(gB0b, lB0b); gload16(gB1b, lB1b);
    gA0 += 64; gA1 += 64; gB0 += 64; gB1 += 64;
    gA0b += 64; gA1b += 64; gB0b += 64; gB1b += 64;
    __syncthreads();

#pragma unroll
    for (int h = 0; h < 2; ++h) {
      half8_t af[4], bfr[4];
#pragma unroll
      for (int i = 0; i < 4; ++i) af[i]  = *(const half8_t*)&As[h * 4096 + aoff[i]];
#pragma unroll
      for (int j = 0; j < 4; ++j) bfr[j] = *(const half8_t*)&Bs[h * 4096 + boff[j]];
#pragma unroll
      for (int i = 0; i < 4; ++i)
#pragma unroll
        for (int j = 0; j < 4; ++j)
          acc[i][j] = __builtin_amdgcn_mfma_f32_16x16x32_f16(af[i], bfr[j], acc[i][j], 0, 0, 0);
    }
    __syncthreads();
  }

  {
    _Float16* Cp = C + (size_t)z * sC;
#pragma unroll
    for (int i = 0; i < 4; ++i)
#pragma unroll
      for (int r = 0; r < 4; ++r) {
        int gm = row0 + wr * 64 + i * 16 + q * 4 + r;
#pragma unroll
        for (int j = 0; j < 4; ++j) {
          int gn = col0 + wc * 64 + j * 16 + m15;
          Cp[(size_t)gm * ldc + gn] = (_Float16)acc[i][j][r];
        }
      }
  }
}

// ---------------------------------------------------------------------------
// V-GEMM: fp16 NT, 256x256 tile, BK=32, 512 threads = 8 waves (2M x 4N),
// 4-deep LDS ring (4 x 32 KiB), tile t+2 staged during tile t, ONE barrier
// per K-tile, counted vmcnt(4). Conflict-free chunk swizzle (0 measured).
// Fused tanh + column-sum epilogue -> agg. (Unchanged; 143 us / 44% MfmaUtil.)
// ---------------------------------------------------------------------------
__global__ __launch_bounds__(512, 2) void gemm_f16_sum8(
    const _Float16* __restrict__ A, int lda,
    const _Float16* __restrict__ B, int ldb,
    int K, float* __restrict__ agg)
{
  __shared__ __align__(16) _Float16 LDS[4][2 * 256 * 32];

  const int row0 = blockIdx.x * 256;
  const int col0 = blockIdx.y * 256;
  const int tid  = threadIdx.x;
  const int lane = tid & 63, wave = tid >> 6;
  const int wr = wave >> 2, wc = wave & 3;     // 2 M-waves x 4 N-waves
  const int m15 = lane & 15, q = lane >> 4;
  const int nt = K / 32;

  const int srow = wave * 32 + (lane >> 2);
  const int cg   = ((lane & 3) ^ ((lane >> 3) & 3)) * 8;
  const _Float16* gA = A + (size_t)(row0 + srow) * lda + cg;
  const _Float16* gB = B + (size_t)(col0 + srow) * ldb + cg;

  auto stageA = [&](int t) {
    const _Float16* g = gA + t * 32;
    _Float16* l = &LDS[t & 3][wave * 1024];
    gload16(g, l);
    gload16(g + (size_t)16 * lda, l + 512);
  };
  auto stageB = [&](int t) {
    const _Float16* g = gB + t * 32;
    _Float16* l = &LDS[t & 3][8192 + wave * 1024];
    gload16(g, l);
    gload16(g + (size_t)16 * ldb, l + 512);
  };

  const int xq = (q ^ ((m15 >> 1) & 3)) * 8;
  int aoff[8], boff[4];
#pragma unroll
  for (int i = 0; i < 8; ++i)
    aoff[i] = (wr * 128 + i * 16 + m15) * 32 + xq;
#pragma unroll
  for (int j = 0; j < 4; ++j)
    boff[j] = 8192 + (wc * 64 + j * 16 + m15) * 32 + xq;

  float4_t acc[8][4];
#pragma unroll
  for (int i = 0; i < 8; ++i)
#pragma unroll
    for (int j = 0; j < 4; ++j) acc[i][j] = (float4_t)0.0f;

  stageA(0); stageB(0);
  stageA(1); stageB(1);
  asm volatile("s_waitcnt vmcnt(4)");
  __builtin_amdgcn_s_barrier();

  for (int t = 0; t < nt; ++t) {
    const _Float16* buf = &LDS[t & 3][0];
    __builtin_amdgcn_sched_barrier(0);

    half8_t a0[4], a1[4], bb[4];
#pragma unroll
    for (int i = 0; i < 4; ++i) a0[i] = *(const half8_t*)&buf[aoff[i]];
#pragma unroll
    for (int j = 0; j < 4; ++j) bb[j] = *(const half8_t*)&buf[boff[j]];
#pragma unroll
    for (int i = 0; i < 4; ++i) a1[i] = *(const half8_t*)&buf[aoff[4 + i]];

    if (t + 2 < nt) { stageA(t + 2); stageB(t + 2); }

    __builtin_amdgcn_s_setprio(1);
#pragma unroll
    for (int i = 0; i < 4; ++i)
#pragma unroll
      for (int j = 0; j < 4; ++j)
        acc[i][j] = __builtin_amdgcn_mfma_f32_16x16x32_f16(a0[i], bb[j], acc[i][j], 0, 0, 0);
#pragma unroll
    for (int i = 0; i < 4; ++i)
#pragma unroll
      for (int j = 0; j < 4; ++j)
        acc[4 + i][j] = __builtin_amdgcn_mfma_f32_16x16x32_f16(a1[i], bb[j], acc[4 + i][j], 0, 0, 0);
    __builtin_amdgcn_s_setprio(0);

    __builtin_amdgcn_sched_barrier(0);
    if (t + 2 < nt) {
      asm volatile("s_waitcnt vmcnt(4)");
    } else if (t + 1 < nt) {
      asm volatile("s_waitcnt vmcnt(0)");
    }
    __builtin_amdgcn_s_barrier();
  }

  // ---- epilogue: tanh + column-sum -> agg[b][half*2048 + col] ----
  const int half_ = row0 >= 8192;
  const int b     = (row0 & 8191) >> 8;
#pragma unroll
  for (int j = 0; j < 4; ++j) {
    float s = 0.0f;
#pragma unroll
    for (int i = 0; i < 8; ++i)
#pragma unroll
      for (int r = 0; r < 4; ++r) s += fast_tanh(acc[i][j][r]);
    s += __shfl_xor(s, 16);
    s += __shfl_xor(s, 32);
    if (q == 0) {
      int col = col0 + wc * 64 + j * 16 + m15;
      atomicAdd(&agg[(size_t)b * 4096 + half_ * 2048 + col], s);
    }
  }
}

// ---------------------------------------------------------------------------
// Merged weight transpose: blocks 0..1023 = W_F [1024][1024] -> split bf16
// transpose; blocks 1024..5119 = W_G [2048][2048] -> fp16 transpose.
// One launch instead of two.
// ---------------------------------------------------------------------------
__global__ __launch_bounds__(256) void transpose_w(
    const float* __restrict__ WF, short* __restrict__ oh, short* __restrict__ ol,
    const float* __restrict__ WG, _Float16* __restrict__ og)
{
  __shared__ float tile[32][33];
  const int id = blockIdx.x;
  const int tx = threadIdx.x & 31, ty = threadIdx.x >> 5;
  if (id < 1024) {
    const int c0 = (id & 31) * 32, r0 = (id >> 5) * 32;   // over [1024][1024]
#pragma unroll
    for (int i = 0; i < 4; ++i) {
      int r = ty + i * 8;
      tile[r][tx] = WF[(size_t)(r0 + r) * 1024 + c0 + tx];
    }
    __syncthreads();
#pragma unroll
    for (int i = 0; i < 4; ++i) {
      int cc = ty + i * 8;
      float v = tile[tx][cc];
      short hi, lo; split2(v, hi, lo);
      size_t o = (size_t)(c0 + cc) * 1024 + r0 + tx;
      oh[o] = hi;
      ol[o] = lo;
    }
  } else {
    const int t2 = id - 1024;
    const int c0 = (t2 & 63) * 32, r0 = (t2 >> 6) * 32;   // over [2048][2048]
#pragma unroll
    for (int i = 0; i < 4; ++i) {
      int r = ty + i * 8;
      tile[r][tx] = WG[(size_t)(r0 + r) * 2048 + c0 + tx];
    }
    __syncthreads();
#pragma unroll
    for (int i = 0; i < 4; ++i) {
      int cc = ty + i * 8;
      og[(size_t)(c0 + cc) * 2048 + r0 + tx] = (_Float16)tile[tx][cc];
    }
  }
}

// --- fp16 [256x256] batched transpose (attn -> attnT) ---
__global__ __launch_bounds__(256) void transpose_b2b(
    const short* __restrict__ in, short* __restrict__ out,
    int R, int C, long sIn, long sOut)
{
  __shared__ short tile[32][33];
  in  += (size_t)blockIdx.z * sIn;
  out += (size_t)blockIdx.z * sOut;
  const int tx = threadIdx.x & 31, ty = threadIdx.x >> 5;
  const int c0 = blockIdx.x * 32, r0 = blockIdx.y * 32;
#pragma unroll
  for (int i = 0; i < 4; ++i) {
    int r = ty + i * 8;
    tile[r][tx] = in[(size_t)(r0 + r) * C + c0 + tx];
  }
  __syncthreads();
#pragma unroll
  for (int i = 0; i < 4; ++i) {
    int cc = ty + i * 8;
    out[(size_t)(c0 + cc) * R + r0 + tx] = tile[tx][cc];
  }
}

// ---------------------------------------------------------------------------
// Fused input conversion + transpose, vectorized. One pass over P/H producing
// (a) split bf16 planes, (b) fp16 Cat left half, (c) fp16 per-batch transpose
// PHbT[z][1024][256] (z<32 = P^T, z>=32 = H^T). Also zeros agg (512 KB) as a
// side task of the first 128 blocks (removes a launch).
// grid (16, 4, 64): x = 64-col tile over 1024, y = 64-row tile over 256.
// ---------------------------------------------------------------------------
__global__ __launch_bounds__(256) void conv_in_t(
    const float* __restrict__ P, const float* __restrict__ Hh,
    short* __restrict__ oh, short* __restrict__ ol,
    _Float16* __restrict__ cat, _Float16* __restrict__ phbt,
    float* __restrict__ agg)
{
  __shared__ __align__(16) float tile[64][68];   // 272B rows, 16B-aligned
  const int zb   = blockIdx.z;
  const int half = zb >> 5, b = zb & 31;
  // side task: agg zero (32*4096 floats = 512 KB) by the first 128 blocks
  const int bid = (zb * 4 + blockIdx.y) * 16 + blockIdx.x;
  if (bid < 128) {
    float4_t zz = (float4_t)0.0f;
    *(float4_t*)&agg[(size_t)bid * 1024 + threadIdx.x * 4] = zz;
  }
  const float* in = (half ? Hh : P) + (size_t)b * 256 * 1024;
  const int c0 = blockIdx.x * 64;   // col in [0,1024)
  const int r0 = blockIdx.y * 64;   // row in [0,256)
  const int t  = threadIdx.x;
  const int rl = t >> 4;            // 0..15
  const int c4 = (t & 15) * 4;      // 0,4,...,60
  const size_t rowbase = (size_t)half * 8192 + (size_t)b * 256;
#pragma unroll
  for (int i = 0; i < 4; ++i) {
    int r = rl + i * 16;
    float4 v = *(const float4*)&in[(size_t)(r0 + r) * 1024 + c0 + c4];
    *(float4*)&tile[r][c4] = v;
    short4 h, l;
    split2(v.x, h.x, l.x); split2(v.y, h.y, l.y);
    split2(v.z, h.z, l.z); split2(v.w, h.w, l.w);
    size_t o = (rowbase + r0 + r) * 1024 + c0 + c4;
    *(short4*)&oh[o] = h;
    *(short4*)&ol[o] = l;
    half4_t c16;
    c16.x = (_Float16)v.x; c16.y = (_Float16)v.y;
    c16.z = (_Float16)v.z; c16.w = (_Float16)v.w;
    *(half4_t*)&cat[(rowbase + r0 + r) * 2048 + c0 + c4] = c16;
  }
  __syncthreads();
  _Float16* op = phbt + (size_t)zb * 1024 * 256;
  const int tx = t & 31;            // row-pair index: rows 2tx, 2tx+1
  const int w  = t >> 5;            // 0..7
#pragma unroll
  for (int i = 0; i < 8; ++i) {
    int cc = w + i * 8;             // 0..63
    half2_t p;
    p.x = (_Float16)tile[tx * 2][cc];
    p.y = (_Float16)tile[tx * 2 + 1][cc];
    *(half2_t*)&op[(size_t)(c0 + cc) * 256 + r0 + tx * 2] = p;
  }
}

// --- softmax over rows of 256, summing 4 E split-K slice panels,
//     fp32 -> fp16. eparts layout: [zb*4+zk][256][256]. ---
__global__ __launch_bounds__(256) void softmax_rows(
    const float* __restrict__ e, _Float16* __restrict__ attn)
{
  const int row  = blockIdx.x * 4 + (threadIdx.x >> 6);   // 0..8191
  const int lane = threadIdx.x & 63;
  const size_t base = ((size_t)(row >> 8) * 4) * 65536
                    + (size_t)(row & 255) * 256 + lane * 4;
  const float4 v0 = *(const float4*)&e[base];
  const float4 v1 = *(const float4*)&e[base + 65536];
  const float4 v2 = *(const float4*)&e[base + 2 * 65536];
  const float4 v3 = *(const float4*)&e[base + 3 * 65536];
  float4 v;
  v.x = (v0.x + v1.x) + (v2.x + v3.x);
  v.y = (v0.y + v1.y) + (v2.y + v3.y);
  v.z = (v0.z + v1.z) + (v2.z + v3.z);
  v.w = (v0.w + v1.w) + (v2.w + v3.w);
  float m = fmaxf(fmaxf(v.x, v.y), fmaxf(v.z, v.w));
#pragma unroll
  for (int off = 32; off; off >>= 1) m = fmaxf(m, __shfl_xor(m, off));
  float e0 = __expf(v.x - m), e1 = __expf(v.y - m);
  float e2 = __expf(v.z - m), e3 = __expf(v.w - m);
  float s = e0 + e1 + e2 + e3;
#pragma unroll
  for (int off = 32; off; off >>= 1) s += __shfl_xor(s, off);
  float inv = 1.0f / s;
  half4_t o;
  o.x = (_Float16)(e0 * inv); o.y = (_Float16)(e1 * inv);
  o.z = (_Float16)(e2 * inv); o.w = (_Float16)(e3 * inv);
  *(half4_t*)&attn[(size_t)row * 256 + lane * 4] = o;
}

// ---------------------------------------------------------------------------
// Skinny fp32 GEMM, split-K per-slice panels (no atomics, no pre-zero):
// outp[slice][32][N] = A[32][k-slice] @ B[k-slice][N].
// grid (N/64, K/256); block 256. A-slice transposed in LDS [k][m] (+1 pad).
// ---------------------------------------------------------------------------
__global__ __launch_bounds__(256) void skinny_gemm(
    const float* __restrict__ A, const float* __restrict__ B,
    float* __restrict__ outp, int N, int K)
{
  __shared__ float Asl[256][33];
  const int n0 = blockIdx.x * 64;
  const int k0 = blockIdx.y * 256;
  const int t  = threadIdx.x;
#pragma unroll
  for (int j = 0; j < 32; ++j) {
    Asl[t][j] = A[(size_t)j * K + k0 + t];
  }
  __syncthreads();
  const int l = t & 63, w = t >> 6;
  const int n = n0 + l;
  float acc[8] = {0.f, 0.f, 0.f, 0.f, 0.f, 0.f, 0.f, 0.f};
  const float* Bp = B + (size_t)k0 * N + n;
#pragma unroll 4
  for (int k = 0; k < 256; ++k) {
    float bv = Bp[(size_t)k * N];
#pragma unroll
    for (int m = 0; m < 8; ++m)
      acc[m] += Asl[k][w * 8 + m] * bv;
  }
  float* o = outp + (size_t)blockIdx.y * 32 * N;
#pragma unroll
  for (int m = 0; m < 8; ++m)
    o[(size_t)(w * 8 + m) * N + n] = acc[m];
}

// --- a1 = tanh(sum_slices(parts) + bias), fp32 out ---
__global__ __launch_bounds__(256) void bias_sum_tanh(
    const float* __restrict__ parts, int nslice,
    const float* __restrict__ bias, float* __restrict__ o, int n)
{
  int i = blockIdx.x * 256 + threadIdx.x;
  if (i < n) {
    float s = 0.0f;
    for (int sl = 0; sl < nslice; ++sl) s += parts[(size_t)sl * n + i];
    o[i] = fast_tanh(s + bias[i & 2047]);
  }
}

// --- logits: out[b][0..2] = tanh(sum_8slices(c2parts)[b]+b2) @ W3 + b3 ---
__global__ __launch_bounds__(256) void logits2(
    const float* __restrict__ c2parts, const float* __restrict__ b2,
    const float* __restrict__ W3, const float* __restrict__ b3,
    float* __restrict__ out)
{
  const int b = blockIdx.x, t = threadIdx.x;
  float p0 = 0.f, p1 = 0.f, p2 = 0.f;
  for (int k = t; k < 2048; k += 256) {
    float c = 0.0f;
#pragma unroll
    for (int sl = 0; sl < 8; ++sl) c += c2parts[(size_t)sl * 65536 + b * 2048 + k];
    float a = fast_tanh(c + b2[k]);
    p0 += a * W3[k * 3 + 0];
    p1 += a * W3[k * 3 + 1];
    p2 += a * W3[k * 3 + 2];
  }
#pragma unroll
  for (int off = 32; off; off >>= 1) {
    p0 += __shfl_xor(p0, off);
    p1 += __shfl_xor(p1, off);
    p2 += __shfl_xor(p2, off);
  }
  __shared__ float red[4][3];
  if ((t & 63) == 0) {
    red[t >> 6][0] = p0; red[t >> 6][1] = p1; red[t >> 6][2] = p2;
  }
  __syncthreads();
  if (t < 3) out[b * 3 + t] = b3[t] + red[0][t] + red[1][t] + red[2][t] + red[3][t];
}

extern "C" void kernel_launch(void* const* d_in, const int* in_sizes, int n_in,
                              void* d_out, int out_size, void* d_ws, size_t ws_size,
                              hipStream_t stream) {
  (void)in_sizes; (void)n_in; (void)out_size; (void)ws_size;
  const float* P   = (const float*)d_in[0];
  const float* H   = (const float*)d_in[1];
  const float* W_F = (const float*)d_in[2];
  const float* W_G = (const float*)d_in[3];
  const float* W1  = (const float*)d_in[4];
  const float* b1  = (const float*)d_in[5];
  const float* W2  = (const float*)d_in[6];
  const float* b2  = (const float*)d_in[7];
  const float* W3  = (const float*)d_in[8];
  const float* b3  = (const float*)d_in[9];
  float* out = (float*)d_out;

  char* wsp = (char*)d_ws;
  auto alloc = [&](size_t bytes) {
    char* p = wsp;
    wsp += (bytes + 255) & ~(size_t)255;
    return p;
  };
  short*    Pp_h  = (short*)alloc(16384ull * 1024 * 2);     // [P;H] split planes
  short*    Pp_l  = (short*)alloc(16384ull * 1024 * 2);
  _Float16* Cat16 = (_Float16*)alloc(16384ull * 2048 * 2);  // [P|betas ; H|alphas]
  short*    Fbuf  = (short*)alloc(32ull * 1024 * 1024 * 2); // 64 MB: F planes
  _Float16* PHbT  = (_Float16*)alloc(64ull * 1024 * 256 * 2); // 32 MB: P^T|H^T fp16
  short*    WFT_h = (short*)alloc(1024ull * 1024 * 2);
  short*    WFT_l = (short*)alloc(1024ull * 1024 * 2);
  _Float16* WGT16 = (_Float16*)alloc(2048ull * 2048 * 2);
  _Float16* attn  = (_Float16*)alloc(32ull * 256 * 256 * 2);
  _Float16* attnT = (_Float16*)alloc(32ull * 256 * 256 * 2);
  float*    agg   = (float*)alloc(32ull * 4096 * 4);
  float*    a1f   = (float*)alloc(32ull * 2048 * 4);

  short* F_h = Fbuf;
  short* F_l = Fbuf + 16384ull * 1024;
  // Aliases into Pp planes (dead after the F-projection, step 2):
  //  - eparts: 4 split-K slice panels of E, [zb*4+zk][256][256] fp32 = 32 MB
  //  - c1parts/c2parts: classifier split-K partials (4 MB + 2 MB)
  float* eparts  = (float*)Pp_h;                       // 32 MB <= 33.5 MB
  float* c1parts = (float*)Pp_l;                       // 16 x 32 x 2048 fp32
  float* c2parts = (float*)(Pp_l + 4ull * 1024 * 1024);// 8 x 32 x 2048 fp32

  // 1. fused input conversion + per-batch transpose (+agg zero); W transposes
  conv_in_t<<<dim3(16, 4, 64), 256, 0, stream>>>(P, H, Pp_h, Pp_l, Cat16, PHbT, agg);
  transpose_w<<<5120, 256, 0, stream>>>(W_F, WFT_h, WFT_l, W_G, WGT16);

  // 2. F = tanh([P;H] @ W_F), split bf16x3, split store
  gemm_nt_split<1, 1><<<dim3(128, 8, 1), 256, 0, stream>>>(
      Pp_h, Pp_l, 1024, 0, WFT_h, WFT_l, 1024, 0,
      F_h, F_l, 1024, 0, 16384, 1024, 1);

  // 3. scores E[z] = F_p[z] @ F_h[z]^T, split bf16x3, split-K x4 into
  //    per-slice panels (plain stores; softmax sums the 4 slices)
  gemm_nt_split<0, 2><<<dim3(2, 2, 128), 256, 0, stream>>>(
      F_h, F_l, 1024, 256 * 1024,
      F_h + 8192ull * 1024, F_l + 8192ull * 1024, 1024, 256 * 1024,
      eparts, nullptr, 256, 65536, 256, 1024, 4);

  // 4. softmax (sums 4 E slices) -> fp16 attn; attn^T
  softmax_rows<<<2048, 256, 0, stream>>>(eparts, attn);
  transpose_b2b<<<dim3(8, 8, 32), 256, 0, stream>>>(
      (const short*)attn, (short*)attnT, 256, 256, 65536, 65536);

  // 5. betas (z<32) and alphas (z>=32) in ONE launch
  gemm_f16<<<dim3(2, 8, 64), 256, 0, stream>>>(
      attn, 256, 65536, PHbT, 256, 1024 * 256,
      Cat16 + 1024, 2048, 256 * 2048, 256, 32);

  // 6. V = tanh(Cat @ W_G) fused column-sum -> agg
  gemm_f16_sum8<<<dim3(64, 8, 1), 512, 0, stream>>>(
      Cat16, 2048, WGT16, 2048, 2048, agg);

  // 7. classifier: fp32 skinny split-K GEMMs, per-slice panels, no atomics
  skinny_gemm<<<dim3(32, 16), 256, 0, stream>>>(agg, W1, c1parts, 2048, 4096);
  bias_sum_tanh<<<256, 256, 0, stream>>>(c1parts, 16, b1, a1f, 32 * 2048);
  skinny_gemm<<<dim3(32, 8), 256, 0, stream>>>(a1f, W2, c2parts, 2048, 2048);
  logits2<<<32, 256, 0, stream>>>(c2parts, b2, W3, b3, out);
}

// Round 9
// 547.396 us; speedup vs baseline: 1.0973x; 1.0237x over previous
//
#include <hip/hip_runtime.h>
#include <hip/hip_bf16.h>
#include <stdint.h>

// Shapes: B=32, L=256, D=1024, ALIGN=1024, FF=2048, NC=3
// Precision plan:
//  - F proj (split bf16x3), E scores (split bf16x3): the softmax-sensitive path
//  - attn, betas/alphas: fp16 single, V = tanh(Cat@W_G): fp16 single + colsum
//  - classifier: fp32 VALU skinny GEMM
// Graph plan: 12 launches, no fp32 atomics outside sum8's agg epilogue.

typedef __attribute__((ext_vector_type(8))) short    short8_t;   // 8 bf16
typedef __attribute__((ext_vector_type(4))) float    float4_t;
typedef __attribute__((ext_vector_type(8))) _Float16 half8_t;
typedef __attribute__((ext_vector_type(4))) _Float16 half4_t;
typedef __attribute__((ext_vector_type(2))) _Float16 half2_t;

#define DEVI static __device__ __forceinline__

DEVI short f2bf(float f) {
  union { float f; unsigned u; } v; v.f = f;
  unsigned r = v.u + 0x7fffu + ((v.u >> 16) & 1u);   // RNE
  return (short)(r >> 16);
}
DEVI float bf2f(short s) {
  union { unsigned u; float f; } v;
  v.u = ((unsigned)(unsigned short)s) << 16;
  return v.f;
}
DEVI void split2(float x, short& hi, short& lo) {
  hi = f2bf(x);
  lo = f2bf(x - bf2f(hi));
}
DEVI float fast_tanh(float x) {
  float e = __expf(2.0f * x);
  return 1.0f - 2.0f / (e + 1.0f);
}
DEVI void gload16(const void* g, void* l) {
  // async global->LDS, 16B/lane; LDS dest = wave-uniform base + lane*16
  __builtin_amdgcn_global_load_lds(
      (const __attribute__((address_space(1))) void*)g,
      (__attribute__((address_space(3))) void*)l, 16, 0, 0);
}

// ---------------------------------------------------------------------------
// F-projection GEMM (round 9): split-bf16x3 NT, 128x256 tile, 512 threads =
// 8 waves (2M x 4N), BK=32, ring-3 LDS (3 x 48 KiB = 144 KiB), tile t+2
// staged during tile t (slot (t+2)%3 = (t-1)%3: its reads drained at the
// t-1 end-barrier), ONE barrier per tile, counted vmcnt(6) (6 gload16/wave/
// tile), single tail vmcnt(0). Same schedule family as gemm_f16_sum8
// (which it took from 33->44% MfmaUtil). 48 MFMA : 16 ds_read per wave/tile.
// LDS buffer layout (shorts): flat 768 row-planes of 32:
//   [0,128)=Ah rows, [128,256)=Al, [256,512)=Bh, [512,768)=Bl
// Staging: wave w stages flat rows [w*96, w*96+96) in 6 16-row gload16 calls
// (segment boundaries are multiples of 16 -> each call single-segment).
// Chunk swizzle: source chunk (l&3)^((l>>3)&3) => slot s of row r holds
// chunk s^((r>>1)&3); reads at slot q^((m15>>1)&3). (Proven family.)
// Block swizzle: by = id&3 -> 4 consecutive blocks share the A panel (L2).
// Epilogue: tanh + split2 store to F_h/F_l [16384][1024].
// ---------------------------------------------------------------------------
__global__ __launch_bounds__(512, 2) void gemm_split_f(
    const short* __restrict__ Ah, const short* __restrict__ Al,
    const short* __restrict__ Bh, const short* __restrict__ Bl,
    short* __restrict__ Fh, short* __restrict__ Fl)
{
  __shared__ __align__(16) short LDS[3][24576];   // 3 x 48 KiB

  const int id   = blockIdx.x;
  const int row0 = (id >> 2) * 128;               // over M=16384
  const int col0 = (id & 3) * 256;                // over N=1024
  const int tid  = threadIdx.x;
  const int lane = tid & 63, wave = tid >> 6;
  const int wr = wave >> 2, wc = wave & 3;        // 2 M-waves x 4 N-waves
  const int m15 = lane & 15, q = lane >> 4;
  const int nt = 1024 / 32;                       // 32 K-tiles

  // --- staging addressing ---
  const int cg = ((lane & 3) ^ ((lane >> 3) & 3)) * 8;
  const short* gptr[6];
  int ldsoff[6];
#pragma unroll
  for (int c = 0; c < 6; ++c) {
    const int f0 = wave * 96 + c * 16;
    const int fr = f0 + (lane >> 2);
    const short* base;
    size_t roff;
    if (f0 < 128)      { base = Ah; roff = (size_t)(row0 + fr) * 1024; }
    else if (f0 < 256) { base = Al; roff = (size_t)(row0 + fr - 128) * 1024; }
    else if (f0 < 512) { base = Bh; roff = (size_t)(col0 + fr - 256) * 1024; }
    else               { base = Bl; roff = (size_t)(col0 + fr - 512) * 1024; }
    gptr[c]   = base + roff + cg;
    ldsoff[c] = f0 * 32;
  }
  auto stage = [&](short* slotbase, int kt) {
#pragma unroll
    for (int c = 0; c < 6; ++c)
      gload16(gptr[c] + kt * 32, slotbase + ldsoff[c]);
  };

  // --- fragment read offsets (within a 24576-short buffer) ---
  const int xq = (q ^ ((m15 >> 1) & 3)) * 8;
  int arow[4], brow[4];
#pragma unroll
  for (int i = 0; i < 4; ++i) {
    arow[i] = (wr * 64 + i * 16 + m15) * 32 + xq;          // Ah base 0, Al +4096
    brow[i] = 8192 + (wc * 64 + i * 16 + m15) * 32 + xq;   // Bh base, Bl +8192
  }

  float4_t acc[4][4];
#pragma unroll
  for (int i = 0; i < 4; ++i)
#pragma unroll
    for (int j = 0; j < 4; ++j) acc[i][j] = (float4_t)0.0f;

  // --- prologue: tiles 0,1 staged (12 calls); wait for tile0 (oldest 6) ---
  stage(&LDS[0][0], 0);
  stage(&LDS[1][0], 1);
  asm volatile("s_waitcnt vmcnt(6)");
  __builtin_amdgcn_s_barrier();

  int cur = 0, st2 = 2;
  for (int t = 0; t < nt; ++t) {
    short* buf = &LDS[cur][0];
    __builtin_amdgcn_sched_barrier(0);

    short8_t ah[4], al[4], bh[4], bl[4];
#pragma unroll
    for (int i = 0; i < 4; ++i) {
      ah[i] = *(const short8_t*)&buf[arow[i]];
      al[i] = *(const short8_t*)&buf[arow[i] + 4096];
    }
#pragma unroll
    for (int j = 0; j < 4; ++j) {
      bh[j] = *(const short8_t*)&buf[brow[j]];
      bl[j] = *(const short8_t*)&buf[brow[j] + 8192];
    }

    if (t + 2 < nt) stage(&LDS[st2][0], t + 2);

    __builtin_amdgcn_s_setprio(1);
#pragma unroll
    for (int i = 0; i < 4; ++i)
#pragma unroll
      for (int j = 0; j < 4; ++j) {
        acc[i][j] = __builtin_amdgcn_mfma_f32_16x16x32_bf16(ah[i], bh[j], acc[i][j], 0, 0, 0);
        acc[i][j] = __builtin_amdgcn_mfma_f32_16x16x32_bf16(ah[i], bl[j], acc[i][j], 0, 0, 0);
        acc[i][j] = __builtin_amdgcn_mfma_f32_16x16x32_bf16(al[i], bh[j], acc[i][j], 0, 0, 0);
      }
    __builtin_amdgcn_s_setprio(0);

    __builtin_amdgcn_sched_barrier(0);
    if (t + 2 < nt) {
      asm volatile("s_waitcnt vmcnt(6)");   // tile t+1 resident; t+2 in flight
    } else if (t + 1 < nt) {
      asm volatile("s_waitcnt vmcnt(0)");   // single tail drain
    }
    __builtin_amdgcn_s_barrier();
    cur = (cur == 2) ? 0 : cur + 1;
    st2 = (st2 == 2) ? 0 : st2 + 1;
  }

  // --- epilogue: tanh + split2 store ---
#pragma unroll
  for (int i = 0; i < 4; ++i) {
#pragma unroll
    for (int r = 0; r < 4; ++r) {
      const int gm = row0 + wr * 64 + i * 16 + q * 4 + r;
#pragma unroll
      for (int j = 0; j < 4; ++j) {
        const int gn = col0 + wc * 64 + j * 16 + m15;
        float v = fast_tanh(acc[i][j][r]);
        short hi, lo; split2(v, hi, lo);
        Fh[(size_t)gm * 1024 + gn] = hi;
        Fl[(size_t)gm * 1024 + gn] = lo;
      }
    }
  }
}

// ---------------------------------------------------------------------------
// Split-bf16 NT GEMM (A=Ah+Al, B=Bh+Bl), 128x128 tile, BK=32, 4 waves,
// 3 MFMAs per product (hh,hl,lh). blockIdx.z = batch*kslices + kslice.
// OUT_MODE: 2 = plain fp32 store, C panel index z (per-slice split-K panels;
//               consumer sums the kslices — no atomics, no pre-zero)
// Used for the E-scores only (F-projection moved to gemm_split_f).
// ---------------------------------------------------------------------------
template <int DO_TANH, int OUT_MODE>
__global__ __launch_bounds__(256) void gemm_nt_split(
    const short* __restrict__ Ah, const short* __restrict__ Al, int lda, long sA,
    const short* __restrict__ Bh, const short* __restrict__ Bl, int ldb, long sB,
    void* __restrict__ Ch, void* __restrict__ Cl, int ldc, long sC,
    int M, int K, int kslices)
{
  __shared__ __align__(16) short Ash[128 * 32];
  __shared__ __align__(16) short Asl[128 * 32];
  __shared__ __align__(16) short Bsh[128 * 32];
  __shared__ __align__(16) short Bsl[128 * 32];

  const int z  = blockIdx.z;
  const int zb = z / kslices;
  const int Ksub = K / kslices;
  const int zk = z - zb * kslices;
  const int kbeg = zk * Ksub, kend = kbeg + Ksub;

  Ah += (size_t)zb * sA;  Al += (size_t)zb * sA;
  Bh += (size_t)zb * sB;  Bl += (size_t)zb * sB;

  const int row0 = blockIdx.x * 128;
  const int col0 = blockIdx.y * 128;

  const int t    = threadIdx.x;
  const int lane = t & 63;
  const int wave = t >> 6;
  const int wr = wave >> 1, wc = wave & 1;
  const int m15 = lane & 15, q = lane >> 4;

  const int schk = ((t & 3) ^ ((t >> 3) & 3)) * 8;
  const short* pAh = Ah + (size_t)(row0 + (t >> 2)) * lda + kbeg + schk;
  const short* pAl = Al + (size_t)(row0 + (t >> 2)) * lda + kbeg + schk;
  const short* pBh = Bh + (size_t)(col0 + (t >> 2)) * ldb + kbeg + schk;
  const short* pBl = Bl + (size_t)(col0 + (t >> 2)) * ldb + kbeg + schk;
  const size_t a64 = (size_t)64 * lda, b64 = (size_t)64 * ldb;
  short* lAh = &Ash[wave * 512];
  short* lAl = &Asl[wave * 512];
  short* lBh = &Bsh[wave * 512];
  short* lBl = &Bsl[wave * 512];

  const int fs2 = (q ^ ((m15 >> 1) & 3)) * 8;

  float4_t acc[4][4];
#pragma unroll
  for (int i = 0; i < 4; ++i)
#pragma unroll
    for (int j = 0; j < 4; ++j) acc[i][j] = (float4_t)0.0f;

  for (int k0 = kbeg; k0 < kend; k0 += 32) {
    gload16(pAh, lAh);  gload16(pAh + a64, lAh + 2048);
    gload16(pAl, lAl);  gload16(pAl + a64, lAl + 2048);
    gload16(pBh, lBh);  gload16(pBh + b64, lBh + 2048);
    gload16(pBl, lBl);  gload16(pBl + b64, lBl + 2048);
    pAh += 32; pAl += 32; pBh += 32; pBl += 32;
    __syncthreads();

    short8_t ah[4], al[4];
#pragma unroll
    for (int i = 0; i < 4; ++i) {
      const int ra = (wr * 64 + i * 16 + m15) * 32 + fs2;
      ah[i] = *(const short8_t*)&Ash[ra];
      al[i] = *(const short8_t*)&Asl[ra];
    }
#pragma unroll
    for (int j = 0; j < 4; ++j) {
      const int rb = (wc * 64 + j * 16 + m15) * 32 + fs2;
      short8_t bh = *(const short8_t*)&Bsh[rb];
      short8_t bl = *(const short8_t*)&Bsl[rb];
#pragma unroll
      for (int i = 0; i < 4; ++i) {
        acc[i][j] = __builtin_amdgcn_mfma_f32_16x16x32_bf16(ah[i], bh, acc[i][j], 0, 0, 0);
        acc[i][j] = __builtin_amdgcn_mfma_f32_16x16x32_bf16(ah[i], bl, acc[i][j], 0, 0, 0);
        acc[i][j] = __builtin_amdgcn_mfma_f32_16x16x32_bf16(al[i], bh, acc[i][j], 0, 0, 0);
      }
    }
    __syncthreads();
  }

  short* Chs = (short*)Ch + (size_t)zb * sC;
  short* Cls = (short*)Cl + (size_t)zb * sC;
  float* Cf  = (float*)Ch + (size_t)(OUT_MODE == 2 ? z : zb) * sC;
#pragma unroll
  for (int i = 0; i < 4; ++i) {
#pragma unroll
    for (int r = 0; r < 4; ++r) {
      int gm = row0 + wr * 64 + i * 16 + q * 4 + r;
      if (gm < M) {
#pragma unroll
        for (int j = 0; j < 4; ++j) {
          int gn = col0 + wc * 64 + j * 16 + m15;
          float v = acc[i][j][r];
          if (DO_TANH) v = fast_tanh(v);
          if (OUT_MODE == 2) {
            Cf[(size_t)gm * ldc + gn] = v;
          } else {
            short hi, lo; split2(v, hi, lo);
            Chs[(size_t)gm * ldc + gn] = hi;
            Cls[(size_t)gm * ldc + gn] = lo;
          }
        }
      }
    }
  }
}

// ---------------------------------------------------------------------------
// fp16 single-pass NT GEMM, BK=64, async global_load_lds staging, XOR
// chunk-swizzled unpadded LDS (0 bank conflicts). fp16 store.
// B batch index = z ^ bxor (one launch covers betas (z<32, B=H^T) and
// alphas (z>=32, B=P^T) with PHbT layout [P^T batches | H^T batches]).
// K % 64 == 0.
// ---------------------------------------------------------------------------
__global__ __launch_bounds__(256) void gemm_f16(
    const _Float16* __restrict__ A, int lda, long sA,
    const _Float16* __restrict__ B, int ldb, long sB,
    _Float16* __restrict__ C, int ldc, long sC,
    int K, int bxor)
{
  __shared__ __align__(16) _Float16 As[2 * 128 * 32];
  __shared__ __align__(16) _Float16 Bs[2 * 128 * 32];

  const int z = blockIdx.z;
  A += (size_t)z * sA;
  B += (size_t)(z ^ bxor) * sB;

  const int row0 = blockIdx.x * 128;
  const int col0 = blockIdx.y * 128;
  const int t = threadIdx.x, lane = t & 63, wave = t >> 6;
  const int wr = wave >> 1, wc = wave & 1;
  const int m15 = lane & 15, q = lane >> 4;

  const int srow = wave * 32 + (lane >> 2);
  const int cg   = ((lane & 3) ^ ((lane >> 3) & 3)) * 8;
  const _Float16* gA0 = A + (size_t)(row0 + srow) * lda + cg;
  const _Float16* gA1 = gA0 + (size_t)16 * lda;
  const _Float16* gB0 = B + (size_t)(col0 + srow) * ldb + cg;
  const _Float16* gB1 = gB0 + (size_t)16 * ldb;
  const _Float16* gA0b = gA0 + 32;
  const _Float16* gA1b = gA1 + 32;
  const _Float16* gB0b = gB0 + 32;
  const _Float16* gB1b = gB1 + 32;
  _Float16* lA0  = &As[(wave * 32) * 32];
  _Float16* lA1  = &As[(wave * 32 + 16) * 32];
  _Float16* lB0  = &Bs[(wave * 32) * 32];
  _Float16* lB1  = &Bs[(wave * 32 + 16) * 32];
  _Float16* lA0b = lA0 + 4096;
  _Float16* lA1b = lA1 + 4096;
  _Float16* lB0b = lB0 + 4096;
  _Float16* lB1b = lB1 + 4096;

  const int fs = (q ^ ((m15 >> 1) & 3)) * 8;
  int aoff[4], boff[4];
#pragma unroll
  for (int i = 0; i < 4; ++i) {
    aoff[i] = (wr * 64 + i * 16 + m15) * 32 + fs;
    boff[i] = (wc * 64 + i * 16 + m15) * 32 + fs;
  }

  float4_t acc[4][4];
#pragma unroll
  for (int i = 0; i < 4; ++i)
#pragma unroll
    for (int j = 0; j < 4; ++j) acc[i][j] = (float4_t)0.0f;

  for (int k0 = 0; k0 < K; k0 += 64) {
    gload16(gA0, lA0);  gload16(gA1, lA1);
    gload16(gB0, lB0);  gload16(gB1, lB1);
    gload16(gA0b, lA0b); gload16(gA1b, lA1b);
    gload16(gB0b, lB0b); gload16(gB1b, lB1b);
    gA0 += 64; gA1 += 64; gB0 += 64; gB1 += 64;
    gA0b += 64; gA1b += 64; gB0b += 64; gB1b += 64;
    __syncthreads();

#pragma unroll
    for (int h = 0; h < 2; ++h) {
      half8_t af[4], bfr[4];
#pragma unroll
      for (int i = 0; i < 4; ++i) af[i]  = *(const half8_t*)&As[h * 4096 + aoff[i]];
#pragma unroll
      for (int j = 0; j < 4; ++j) bfr[j] = *(const half8_t*)&Bs[h * 4096 + boff[j]];
#pragma unroll
      for (int i = 0; i < 4; ++i)
#pragma unroll
        for (int j = 0; j < 4; ++j)
          acc[i][j] = __builtin_amdgcn_mfma_f32_16x16x32_f16(af[i], bfr[j], acc[i][j], 0, 0, 0);
    }
    __syncthreads();
  }

  {
    _Float16* Cp = C + (size_t)z * sC;
#pragma unroll
    for (int i = 0; i < 4; ++i)
#pragma unroll
      for (int r = 0; r < 4; ++r) {
        int gm = row0 + wr * 64 + i * 16 + q * 4 + r;
#pragma unroll
        for (int j = 0; j < 4; ++j) {
          int gn = col0 + wc * 64 + j * 16 + m15;
          Cp[(size_t)gm * ldc + gn] = (_Float16)acc[i][j][r];
        }
      }
  }
}

// ---------------------------------------------------------------------------
// V-GEMM: fp16 NT, 256x256 tile, BK=32, 512 threads = 8 waves (2M x 4N),
// 4-deep LDS ring (4 x 32 KiB), tile t+2 staged during tile t, ONE barrier
// per K-tile, counted vmcnt(4). Conflict-free chunk swizzle (0 measured).
// Fused tanh + column-sum epilogue -> agg. (Unchanged; 143-161 us band.)
// ---------------------------------------------------------------------------
__global__ __launch_bounds__(512, 2) void gemm_f16_sum8(
    const _Float16* __restrict__ A, int lda,
    const _Float16* __restrict__ B, int ldb,
    int K, float* __restrict__ agg)
{
  __shared__ __align__(16) _Float16 LDS[4][2 * 256 * 32];

  const int row0 = blockIdx.x * 256;
  const int col0 = blockIdx.y * 256;
  const int tid  = threadIdx.x;
  const int lane = tid & 63, wave = tid >> 6;
  const int wr = wave >> 2, wc = wave & 3;     // 2 M-waves x 4 N-waves
  const int m15 = lane & 15, q = lane >> 4;
  const int nt = K / 32;

  const int srow = wave * 32 + (lane >> 2);
  const int cg   = ((lane & 3) ^ ((lane >> 3) & 3)) * 8;
  const _Float16* gA = A + (size_t)(row0 + srow) * lda + cg;
  const _Float16* gB = B + (size_t)(col0 + srow) * ldb + cg;

  auto stageA = [&](int t) {
    const _Float16* g = gA + t * 32;
    _Float16* l = &LDS[t & 3][wave * 1024];
    gload16(g, l);
    gload16(g + (size_t)16 * lda, l + 512);
  };
  auto stageB = [&](int t) {
    const _Float16* g = gB + t * 32;
    _Float16* l = &LDS[t & 3][8192 + wave * 1024];
    gload16(g, l);
    gload16(g + (size_t)16 * ldb, l + 512);
  };

  const int xq = (q ^ ((m15 >> 1) & 3)) * 8;
  int aoff[8], boff[4];
#pragma unroll
  for (int i = 0; i < 8; ++i)
    aoff[i] = (wr * 128 + i * 16 + m15) * 32 + xq;
#pragma unroll
  for (int j = 0; j < 4; ++j)
    boff[j] = 8192 + (wc * 64 + j * 16 + m15) * 32 + xq;

  float4_t acc[8][4];
#pragma unroll
  for (int i = 0; i < 8; ++i)
#pragma unroll
    for (int j = 0; j < 4; ++j) acc[i][j] = (float4_t)0.0f;

  stageA(0); stageB(0);
  stageA(1); stageB(1);
  asm volatile("s_waitcnt vmcnt(4)");
  __builtin_amdgcn_s_barrier();

  for (int t = 0; t < nt; ++t) {
    const _Float16* buf = &LDS[t & 3][0];
    __builtin_amdgcn_sched_barrier(0);

    half8_t a0[4], a1[4], bb[4];
#pragma unroll
    for (int i = 0; i < 4; ++i) a0[i] = *(const half8_t*)&buf[aoff[i]];
#pragma unroll
    for (int j = 0; j < 4; ++j) bb[j] = *(const half8_t*)&buf[boff[j]];
#pragma unroll
    for (int i = 0; i < 4; ++i) a1[i] = *(const half8_t*)&buf[aoff[4 + i]];

    if (t + 2 < nt) { stageA(t + 2); stageB(t + 2); }

    __builtin_amdgcn_s_setprio(1);
#pragma unroll
    for (int i = 0; i < 4; ++i)
#pragma unroll
      for (int j = 0; j < 4; ++j)
        acc[i][j] = __builtin_amdgcn_mfma_f32_16x16x32_f16(a0[i], bb[j], acc[i][j], 0, 0, 0);
#pragma unroll
    for (int i = 0; i < 4; ++i)
#pragma unroll
      for (int j = 0; j < 4; ++j)
        acc[4 + i][j] = __builtin_amdgcn_mfma_f32_16x16x32_f16(a1[i], bb[j], acc[4 + i][j], 0, 0, 0);
    __builtin_amdgcn_s_setprio(0);

    __builtin_amdgcn_sched_barrier(0);
    if (t + 2 < nt) {
      asm volatile("s_waitcnt vmcnt(4)");
    } else if (t + 1 < nt) {
      asm volatile("s_waitcnt vmcnt(0)");
    }
    __builtin_amdgcn_s_barrier();
  }

  // ---- epilogue: tanh + column-sum -> agg[b][half*2048 + col] ----
  const int half_ = row0 >= 8192;
  const int b     = (row0 & 8191) >> 8;
#pragma unroll
  for (int j = 0; j < 4; ++j) {
    float s = 0.0f;
#pragma unroll
    for (int i = 0; i < 8; ++i)
#pragma unroll
      for (int r = 0; r < 4; ++r) s += fast_tanh(acc[i][j][r]);
    s += __shfl_xor(s, 16);
    s += __shfl_xor(s, 32);
    if (q == 0) {
      int col = col0 + wc * 64 + j * 16 + m15;
      atomicAdd(&agg[(size_t)b * 4096 + half_ * 2048 + col], s);
    }
  }
}

// ---------------------------------------------------------------------------
// Merged weight transpose: blocks 0..1023 = W_F [1024][1024] -> split bf16
// transpose; blocks 1024..5119 = W_G [2048][2048] -> fp16 transpose.
// ---------------------------------------------------------------------------
__global__ __launch_bounds__(256) void transpose_w(
    const float* __restrict__ WF, short* __restrict__ oh, short* __restrict__ ol,
    const float* __restrict__ WG, _Float16* __restrict__ og)
{
  __shared__ float tile[32][33];
  const int id = blockIdx.x;
  const int tx = threadIdx.x & 31, ty = threadIdx.x >> 5;
  if (id < 1024) {
    const int c0 = (id & 31) * 32, r0 = (id >> 5) * 32;   // over [1024][1024]
#pragma unroll
    for (int i = 0; i < 4; ++i) {
      int r = ty + i * 8;
      tile[r][tx] = WF[(size_t)(r0 + r) * 1024 + c0 + tx];
    }
    __syncthreads();
#pragma unroll
    for (int i = 0; i < 4; ++i) {
      int cc = ty + i * 8;
      float v = tile[tx][cc];
      short hi, lo; split2(v, hi, lo);
      size_t o = (size_t)(c0 + cc) * 1024 + r0 + tx;
      oh[o] = hi;
      ol[o] = lo;
    }
  } else {
    const int t2 = id - 1024;
    const int c0 = (t2 & 63) * 32, r0 = (t2 >> 6) * 32;   // over [2048][2048]
#pragma unroll
    for (int i = 0; i < 4; ++i) {
      int r = ty + i * 8;
      tile[r][tx] = WG[(size_t)(r0 + r) * 2048 + c0 + tx];
    }
    __syncthreads();
#pragma unroll
    for (int i = 0; i < 4; ++i) {
      int cc = ty + i * 8;
      og[(size_t)(c0 + cc) * 2048 + r0 + tx] = (_Float16)tile[tx][cc];
    }
  }
}

// --- fp16 [256x256] batched transpose (attn -> attnT) ---
__global__ __launch_bounds__(256) void transpose_b2b(
    const short* __restrict__ in, short* __restrict__ out,
    int R, int C, long sIn, long sOut)
{
  __shared__ short tile[32][33];
  in  += (size_t)blockIdx.z * sIn;
  out += (size_t)blockIdx.z * sOut;
  const int tx = threadIdx.x & 31, ty = threadIdx.x >> 5;
  const int c0 = blockIdx.x * 32, r0 = blockIdx.y * 32;
#pragma unroll
  for (int i = 0; i < 4; ++i) {
    int r = ty + i * 8;
    tile[r][tx] = in[(size_t)(r0 + r) * C + c0 + tx];
  }
  __syncthreads();
#pragma unroll
  for (int i = 0; i < 4; ++i) {
    int cc = ty + i * 8;
    out[(size_t)(c0 + cc) * R + r0 + tx] = tile[tx][cc];
  }
}

// ---------------------------------------------------------------------------
// Fused input conversion + transpose, vectorized. One pass over P/H producing
// (a) split bf16 planes, (b) fp16 Cat left half, (c) fp16 per-batch transpose
// PHbT[z][1024][256] (z<32 = P^T, z>=32 = H^T). Also zeros agg (512 KB) as a
// side task of the first 128 blocks.
// grid (16, 4, 64): x = 64-col tile over 1024, y = 64-row tile over 256.
// ---------------------------------------------------------------------------
__global__ __launch_bounds__(256) void conv_in_t(
    const float* __restrict__ P, const float* __restrict__ Hh,
    short* __restrict__ oh, short* __restrict__ ol,
    _Float16* __restrict__ cat, _Float16* __restrict__ phbt,
    float* __restrict__ agg)
{
  __shared__ __align__(16) float tile[64][68];   // 272B rows, 16B-aligned
  const int zb   = blockIdx.z;
  const int half = zb >> 5, b = zb & 31;
  const int bid = (zb * 4 + blockIdx.y) * 16 + blockIdx.x;
  if (bid < 128) {
    float4_t zz = (float4_t)0.0f;
    *(float4_t*)&agg[(size_t)bid * 1024 + threadIdx.x * 4] = zz;
  }
  const float* in = (half ? Hh : P) + (size_t)b * 256 * 1024;
  const int c0 = blockIdx.x * 64;   // col in [0,1024)
  const int r0 = blockIdx.y * 64;   // row in [0,256)
  const int t  = threadIdx.x;
  const int rl = t >> 4;            // 0..15
  const int c4 = (t & 15) * 4;      // 0,4,...,60
  const size_t rowbase = (size_t)half * 8192 + (size_t)b * 256;
#pragma unroll
  for (int i = 0; i < 4; ++i) {
    int r = rl + i * 16;
    float4 v = *(const float4*)&in[(size_t)(r0 + r) * 1024 + c0 + c4];
    *(float4*)&tile[r][c4] = v;
    short4 h, l;
    split2(v.x, h.x, l.x); split2(v.y, h.y, l.y);
    split2(v.z, h.z, l.z); split2(v.w, h.w, l.w);
    size_t o = (rowbase + r0 + r) * 1024 + c0 + c4;
    *(short4*)&oh[o] = h;
    *(short4*)&ol[o] = l;
    half4_t c16;
    c16.x = (_Float16)v.x; c16.y = (_Float16)v.y;
    c16.z = (_Float16)v.z; c16.w = (_Float16)v.w;
    *(half4_t*)&cat[(rowbase + r0 + r) * 2048 + c0 + c4] = c16;
  }
  __syncthreads();
  _Float16* op = phbt + (size_t)zb * 1024 * 256;
  const int tx = t & 31;            // row-pair index: rows 2tx, 2tx+1
  const int w  = t >> 5;            // 0..7
#pragma unroll
  for (int i = 0; i < 8; ++i) {
    int cc = w + i * 8;             // 0..63
    half2_t p;
    p.x = (_Float16)tile[tx * 2][cc];
    p.y = (_Float16)tile[tx * 2 + 1][cc];
    *(half2_t*)&op[(size_t)(c0 + cc) * 256 + r0 + tx * 2] = p;
  }
}

// --- softmax over rows of 256, summing 4 E split-K slice panels,
//     fp32 -> fp16. eparts layout: [zb*4+zk][256][256]. ---
__global__ __launch_bounds__(256) void softmax_rows(
    const float* __restrict__ e, _Float16* __restrict__ attn)
{
  const int row  = blockIdx.x * 4 + (threadIdx.x >> 6);   // 0..8191
  const int lane = threadIdx.x & 63;
  const size_t base = ((size_t)(row >> 8) * 4) * 65536
                    + (size_t)(row & 255) * 256 + lane * 4;
  const float4 v0 = *(const float4*)&e[base];
  const float4 v1 = *(const float4*)&e[base + 65536];
  const float4 v2 = *(const float4*)&e[base + 2 * 65536];
  const float4 v3 = *(const float4*)&e[base + 3 * 65536];
  float4 v;
  v.x = (v0.x + v1.x) + (v2.x + v3.x);
  v.y = (v0.y + v1.y) + (v2.y + v3.y);
  v.z = (v0.z + v1.z) + (v2.z + v3.z);
  v.w = (v0.w + v1.w) + (v2.w + v3.w);
  float m = fmaxf(fmaxf(v.x, v.y), fmaxf(v.z, v.w));
#pragma unroll
  for (int off = 32; off; off >>= 1) m = fmaxf(m, __shfl_xor(m, off));
  float e0 = __expf(v.x - m), e1 = __expf(v.y - m);
  float e2 = __expf(v.z - m), e3 = __expf(v.w - m);
  float s = e0 + e1 + e2 + e3;
#pragma unroll
  for (int off = 32; off; off >>= 1) s += __shfl_xor(s, off);
  float inv = 1.0f / s;
  half4_t o;
  o.x = (_Float16)(e0 * inv); o.y = (_Float16)(e1 * inv);
  o.z = (_Float16)(e2 * inv); o.w = (_Float16)(e3 * inv);
  *(half4_t*)&attn[(size_t)row * 256 + lane * 4] = o;
}

// ---------------------------------------------------------------------------
// Skinny fp32 GEMM, split-K per-slice panels (no atomics, no pre-zero):
// outp[slice][32][N] = A[32][k-slice] @ B[k-slice][N].
// grid (N/64, K/256); block 256. A-slice transposed in LDS [k][m] (+1 pad).
// ---------------------------------------------------------------------------
__global__ __launch_bounds__(256) void skinny_gemm(
    const float* __restrict__ A, const float* __restrict__ B,
    float* __restrict__ outp, int N, int K)
{
  __shared__ float Asl[256][33];
  const int n0 = blockIdx.x * 64;
  const int k0 = blockIdx.y * 256;
  const int t  = threadIdx.x;
#pragma unroll
  for (int j = 0; j < 32; ++j) {
    Asl[t][j] = A[(size_t)j * K + k0 + t];
  }
  __syncthreads();
  const int l = t & 63, w = t >> 6;
  const int n = n0 + l;
  float acc[8] = {0.f, 0.f, 0.f, 0.f, 0.f, 0.f, 0.f, 0.f};
  const float* Bp = B + (size_t)k0 * N + n;
#pragma unroll 4
  for (int k = 0; k < 256; ++k) {
    float bv = Bp[(size_t)k * N];
#pragma unroll
    for (int m = 0; m < 8; ++m)
      acc[m] += Asl[k][w * 8 + m] * bv;
  }
  float* o = outp + (size_t)blockIdx.y * 32 * N;
#pragma unroll
  for (int m = 0; m < 8; ++m)
    o[(size_t)(w * 8 + m) * N + n] = acc[m];
}

// --- a1 = tanh(sum_slices(parts) + bias), fp32 out ---
__global__ __launch_bounds__(256) void bias_sum_tanh(
    const float* __restrict__ parts, int nslice,
    const float* __restrict__ bias, float* __restrict__ o, int n)
{
  int i = blockIdx.x * 256 + threadIdx.x;
  if (i < n) {
    float s = 0.0f;
    for (int sl = 0; sl < nslice; ++sl) s += parts[(size_t)sl * n + i];
    o[i] = fast_tanh(s + bias[i & 2047]);
  }
}

// --- logits: out[b][0..2] = tanh(sum_8slices(c2parts)[b]+b2) @ W3 + b3 ---
__global__ __launch_bounds__(256) void logits2(
    const float* __restrict__ c2parts, const float* __restrict__ b2,
    const float* __restrict__ W3, const float* __restrict__ b3,
    float* __restrict__ out)
{
  const int b = blockIdx.x, t = threadIdx.x;
  float p0 = 0.f, p1 = 0.f, p2 = 0.f;
  for (int k = t; k < 2048; k += 256) {
    float c = 0.0f;
#pragma unroll
    for (int sl = 0; sl < 8; ++sl) c += c2parts[(size_t)sl * 65536 + b * 2048 + k];
    float a = fast_tanh(c + b2[k]);
    p0 += a * W3[k * 3 + 0];
    p1 += a * W3[k * 3 + 1];
    p2 += a * W3[k * 3 + 2];
  }
#pragma unroll
  for (int off = 32; off; off >>= 1) {
    p0 += __shfl_xor(p0, off);
    p1 += __shfl_xor(p1, off);
    p2 += __shfl_xor(p2, off);
  }
  __shared__ float red[4][3];
  if ((t & 63) == 0) {
    red[t >> 6][0] = p0; red[t >> 6][1] = p1; red[t >> 6][2] = p2;
  }
  __syncthreads();
  if (t < 3) out[b * 3 + t] = b3[t] + red[0][t] + red[1][t] + red[2][t] + red[3][t];
}

extern "C" void kernel_launch(void* const* d_in, const int* in_sizes, int n_in,
                              void* d_out, int out_size, void* d_ws, size_t ws_size,
                              hipStream_t stream) {
  (void)in_sizes; (void)n_in; (void)out_size; (void)ws_size;
  const float* P   = (const float*)d_in[0];
  const float* H   = (const float*)d_in[1];
  const float* W_F = (const float*)d_in[2];
  const float* W_G = (const float*)d_in[3];
  const float* W1  = (const float*)d_in[4];
  const float* b1  = (const float*)d_in[5];
  const float* W2  = (const float*)d_in[6];
  const float* b2  = (const float*)d_in[7];
  const float* W3  = (const float*)d_in[8];
  const float* b3  = (const float*)d_in[9];
  float* out = (float*)d_out;

  char* wsp = (char*)d_ws;
  auto alloc = [&](size_t bytes) {
    char* p = wsp;
    wsp += (bytes + 255) & ~(size_t)255;
    return p;
  };
  short*    Pp_h  = (short*)alloc(16384ull * 1024 * 2);     // [P;H] split planes
  short*    Pp_l  = (short*)alloc(16384ull * 1024 * 2);
  _Float16* Cat16 = (_Float16*)alloc(16384ull * 2048 * 2);  // [P|betas ; H|alphas]
  short*    Fbuf  = (short*)alloc(32ull * 1024 * 1024 * 2); // 64 MB: F planes
  _Float16* PHbT  = (_Float16*)alloc(64ull * 1024 * 256 * 2); // 32 MB: P^T|H^T fp16
  short*    WFT_h = (short*)alloc(1024ull * 1024 * 2);
  short*    WFT_l = (short*)alloc(1024ull * 1024 * 2);
  _Float16* WGT16 = (_Float16*)alloc(2048ull * 2048 * 2);
  _Float16* attn  = (_Float16*)alloc(32ull * 256 * 256 * 2);
  _Float16* attnT = (_Float16*)alloc(32ull * 256 * 256 * 2);
  float*    agg   = (float*)alloc(32ull * 4096 * 4);
  float*    a1f   = (float*)alloc(32ull * 2048 * 4);

  short* F_h = Fbuf;
  short* F_l = Fbuf + 16384ull * 1024;
  // Aliases into Pp planes (dead after the F-projection, step 2):
  float* eparts  = (float*)Pp_h;                       // 32 MB <= 33.5 MB
  float* c1parts = (float*)Pp_l;                       // 16 x 32 x 2048 fp32
  float* c2parts = (float*)(Pp_l + 4ull * 1024 * 1024);// 8 x 32 x 2048 fp32

  // 1. fused input conversion + per-batch transpose (+agg zero); W transposes
  conv_in_t<<<dim3(16, 4, 64), 256, 0, stream>>>(P, H, Pp_h, Pp_l, Cat16, PHbT, agg);
  transpose_w<<<5120, 256, 0, stream>>>(W_F, WFT_h, WFT_l, W_G, WGT16);

  // 2. F = tanh([P;H] @ W_F), split bf16x3, ring-3 counted-vmcnt kernel
  //    (128x256 tile, 512 blocks, by=id&3 so A-panels are L2-shared)
  gemm_split_f<<<512, 512, 0, stream>>>(Pp_h, Pp_l, WFT_h, WFT_l, F_h, F_l);

  // 3. scores E[z] = F_p[z] @ F_h[z]^T, split bf16x3, split-K x4 into
  //    per-slice panels (plain stores; softmax sums the 4 slices)
  gemm_nt_split<0, 2><<<dim3(2, 2, 128), 256, 0, stream>>>(
      F_h, F_l, 1024, 256 * 1024,
      F_h + 8192ull * 1024, F_l + 8192ull * 1024, 1024, 256 * 1024,
      eparts, nullptr, 256, 65536, 256, 1024, 4);

  // 4. softmax (sums 4 E slices) -> fp16 attn; attn^T
  softmax_rows<<<2048, 256, 0, stream>>>(eparts, attn);
  transpose_b2b<<<dim3(8, 8, 32), 256, 0, stream>>>(
      (const short*)attn, (short*)attnT, 256, 256, 65536, 65536);

  // 5. betas (z<32) and alphas (z>=32) in ONE launch
  gemm_f16<<<dim3(2, 8, 64), 256, 0, stream>>>(
      attn, 256, 65536, PHbT, 256, 1024 * 256,
      Cat16 + 1024, 2048, 256 * 2048, 256, 32);

  // 6. V = tanh(Cat @ W_G) fused column-sum -> agg
  gemm_f16_sum8<<<dim3(64, 8, 1), 512, 0, stream>>>(
      Cat16, 2048, WGT16, 2048, 2048, agg);

  // 7. classifier: fp32 skinny split-K GEMMs, per-slice panels, no atomics
  skinny_gemm<<<dim3(32, 16), 256, 0, stream>>>(agg, W1, c1parts, 2048, 4096);
  bias_sum_tanh<<<256, 256, 0, stream>>>(c1parts, 16, b1, a1f, 32 * 2048);
  skinny_gemm<<<dim3(32, 8), 256, 0, stream>>>(a1f, W2, c2parts, 2048, 2048);
  logits2<<<32, 256, 0, stream>>>(c2parts, b2, W3, b3, out);
}

// Round 11
// 543.410 us; speedup vs baseline: 1.1053x; 1.0073x over previous
//
#include <hip/hip_runtime.h>
#include <hip/hip_bf16.h>
#include <stdint.h>

// Shapes: B=32, L=256, D=1024, ALIGN=1024, FF=2048, NC=3
// Precision plan:
//  - F proj (split bf16x3), E scores (split bf16x3): the softmax-sensitive path
//  - attn, betas/alphas: fp16 single, V = tanh(Cat@W_G): fp16 single + colsum
//  - classifier: fp32 VALU skinny GEMM
// All four MFMA GEMMs use the ring/counted-vmcnt schedule family.

typedef __attribute__((ext_vector_type(8))) short    short8_t;   // 8 bf16
typedef __attribute__((ext_vector_type(4))) float    float4_t;
typedef __attribute__((ext_vector_type(8))) _Float16 half8_t;
typedef __attribute__((ext_vector_type(4))) _Float16 half4_t;
typedef __attribute__((ext_vector_type(2))) _Float16 half2_t;

#define DEVI static __device__ __forceinline__

DEVI short f2bf(float f) {
  union { float f; unsigned u; } v; v.f = f;
  unsigned r = v.u + 0x7fffu + ((v.u >> 16) & 1u);   // RNE
  return (short)(r >> 16);
}
DEVI float bf2f(short s) {
  union { unsigned u; float f; } v;
  v.u = ((unsigned)(unsigned short)s) << 16;
  return v.f;
}
DEVI void split2(float x, short& hi, short& lo) {
  hi = f2bf(x);
  lo = f2bf(x - bf2f(hi));
}
DEVI float fast_tanh(float x) {
  float e = __expf(2.0f * x);
  return 1.0f - 2.0f / (e + 1.0f);
}
DEVI void gload16(const void* g, void* l) {
  // async global->LDS, 16B/lane; LDS dest = wave-uniform base + lane*16
  __builtin_amdgcn_global_load_lds(
      (const __attribute__((address_space(1))) void*)g,
      (__attribute__((address_space(3))) void*)l, 16, 0, 0);
}

// ---------------------------------------------------------------------------
// F-projection GEMM: split-bf16x3 NT, 128x256 tile, 512 threads = 8 waves
// (2M x 4N), BK=32, ring-3 LDS (3 x 48 KiB), tile t+2 staged during tile t,
// ONE barrier per tile, counted vmcnt(6), single tail vmcnt(0).
// LDS buffer (shorts): flat 768 row-planes of 32:
//   [0,128)=Ah rows, [128,256)=Al, [256,512)=Bh, [512,768)=Bl
// Chunk swizzle: source chunk (l&3)^((l>>3)&3) => slot s of row r holds
// chunk s^((r>>1)&3); reads at slot q^((m15>>1)&3).
// Block swizzle: by = id&3 -> 4 consecutive blocks share the A panel (L2).
// Epilogue: tanh + split2 store to F_h/F_l [16384][1024].
// ---------------------------------------------------------------------------
__global__ __launch_bounds__(512, 2) void gemm_split_f(
    const short* __restrict__ Ah, const short* __restrict__ Al,
    const short* __restrict__ Bh, const short* __restrict__ Bl,
    short* __restrict__ Fh, short* __restrict__ Fl)
{
  __shared__ __align__(16) short LDS[3][24576];   // 3 x 48 KiB

  const int id   = blockIdx.x;
  const int row0 = (id >> 2) * 128;               // over M=16384
  const int col0 = (id & 3) * 256;                // over N=1024
  const int tid  = threadIdx.x;
  const int lane = tid & 63, wave = tid >> 6;
  const int wr = wave >> 2, wc = wave & 3;        // 2 M-waves x 4 N-waves
  const int m15 = lane & 15, q = lane >> 4;
  const int nt = 1024 / 32;                       // 32 K-tiles

  const int cg = ((lane & 3) ^ ((lane >> 3) & 3)) * 8;
  const short* gptr[6];
  int ldsoff[6];
#pragma unroll
  for (int c = 0; c < 6; ++c) {
    const int f0 = wave * 96 + c * 16;
    const int fr = f0 + (lane >> 2);
    const short* base;
    size_t roff;
    if (f0 < 128)      { base = Ah; roff = (size_t)(row0 + fr) * 1024; }
    else if (f0 < 256) { base = Al; roff = (size_t)(row0 + fr - 128) * 1024; }
    else if (f0 < 512) { base = Bh; roff = (size_t)(col0 + fr - 256) * 1024; }
    else               { base = Bl; roff = (size_t)(col0 + fr - 512) * 1024; }
    gptr[c]   = base + roff + cg;
    ldsoff[c] = f0 * 32;
  }
  auto stage = [&](short* slotbase, int kt) {
#pragma unroll
    for (int c = 0; c < 6; ++c)
      gload16(gptr[c] + kt * 32, slotbase + ldsoff[c]);
  };

  const int xq = (q ^ ((m15 >> 1) & 3)) * 8;
  int arow[4], brow[4];
#pragma unroll
  for (int i = 0; i < 4; ++i) {
    arow[i] = (wr * 64 + i * 16 + m15) * 32 + xq;          // Ah base 0, Al +4096
    brow[i] = 8192 + (wc * 64 + i * 16 + m15) * 32 + xq;   // Bh base, Bl +8192
  }

  float4_t acc[4][4];
#pragma unroll
  for (int i = 0; i < 4; ++i)
#pragma unroll
    for (int j = 0; j < 4; ++j) acc[i][j] = (float4_t)0.0f;

  stage(&LDS[0][0], 0);
  stage(&LDS[1][0], 1);
  asm volatile("s_waitcnt vmcnt(6)");
  __builtin_amdgcn_s_barrier();

  int cur = 0, st2 = 2;
  for (int t = 0; t < nt; ++t) {
    short* buf = &LDS[cur][0];
    __builtin_amdgcn_sched_barrier(0);

    short8_t ah[4], al[4], bh[4], bl[4];
#pragma unroll
    for (int i = 0; i < 4; ++i) {
      ah[i] = *(const short8_t*)&buf[arow[i]];
      al[i] = *(const short8_t*)&buf[arow[i] + 4096];
    }
#pragma unroll
    for (int j = 0; j < 4; ++j) {
      bh[j] = *(const short8_t*)&buf[brow[j]];
      bl[j] = *(const short8_t*)&buf[brow[j] + 8192];
    }

    if (t + 2 < nt) stage(&LDS[st2][0], t + 2);

    __builtin_amdgcn_s_setprio(1);
#pragma unroll
    for (int i = 0; i < 4; ++i)
#pragma unroll
      for (int j = 0; j < 4; ++j) {
        acc[i][j] = __builtin_amdgcn_mfma_f32_16x16x32_bf16(ah[i], bh[j], acc[i][j], 0, 0, 0);
        acc[i][j] = __builtin_amdgcn_mfma_f32_16x16x32_bf16(ah[i], bl[j], acc[i][j], 0, 0, 0);
        acc[i][j] = __builtin_amdgcn_mfma_f32_16x16x32_bf16(al[i], bh[j], acc[i][j], 0, 0, 0);
      }
    __builtin_amdgcn_s_setprio(0);

    __builtin_amdgcn_sched_barrier(0);
    if (t + 2 < nt) {
      asm volatile("s_waitcnt vmcnt(6)");
    } else if (t + 1 < nt) {
      asm volatile("s_waitcnt vmcnt(0)");
    }
    __builtin_amdgcn_s_barrier();
    cur = (cur == 2) ? 0 : cur + 1;
    st2 = (st2 == 2) ? 0 : st2 + 1;
  }

#pragma unroll
  for (int i = 0; i < 4; ++i) {
#pragma unroll
    for (int r = 0; r < 4; ++r) {
      const int gm = row0 + wr * 64 + i * 16 + q * 4 + r;
#pragma unroll
      for (int j = 0; j < 4; ++j) {
        const int gn = col0 + wc * 64 + j * 16 + m15;
        float v = fast_tanh(acc[i][j][r]);
        short hi, lo; split2(v, hi, lo);
        Fh[(size_t)gm * 1024 + gn] = hi;
        Fl[(size_t)gm * 1024 + gn] = lo;
      }
    }
  }
}

// ---------------------------------------------------------------------------
// E-scores GEMM: same ring-3 body as gemm_split_f (identical LDS layout,
// swizzle, vmcnt(6) counting), nt=8. Grid 256 blocks:
// zb = id>>3 (batch), sp = (id>>2)&1 (M-half), zk = id&3 (k-slice).
// A = F premise rows [zb*256+sp*128, +128); B = F hypothesis rows
// [8192+zb*256, +256); K-slice [zk*256, +256). Epilogue: plain fp32 store to
// eparts panel (zb*4+zk) [256][256] (softmax sums the 4 slices).
// ---------------------------------------------------------------------------
__global__ __launch_bounds__(512, 2) void gemm_split_e(
    const short* __restrict__ Fh, const short* __restrict__ Fl,
    float* __restrict__ eparts)
{
  __shared__ __align__(16) short LDS[3][24576];

  const int id = blockIdx.x;
  const int zb = id >> 3;
  const int sp = (id >> 2) & 1;
  const int zk = id & 3;
  const int arow0 = zb * 256 + sp * 128;
  const int brow0 = 8192 + zb * 256;
  const int kbeg  = zk * 256;
  const int tid = threadIdx.x, lane = tid & 63, wave = tid >> 6;
  const int wr = wave >> 2, wc = wave & 3;
  const int m15 = lane & 15, q = lane >> 4;
  const int nt = 8;

  const int cg = ((lane & 3) ^ ((lane >> 3) & 3)) * 8;
  const short* gptr[6];
  int ldsoff[6];
#pragma unroll
  for (int c = 0; c < 6; ++c) {
    const int f0 = wave * 96 + c * 16;
    const int fr = f0 + (lane >> 2);
    const short* base;
    size_t roff;
    if (f0 < 128)      { base = Fh; roff = (size_t)(arow0 + fr) * 1024; }
    else if (f0 < 256) { base = Fl; roff = (size_t)(arow0 + fr - 128) * 1024; }
    else if (f0 < 512) { base = Fh; roff = (size_t)(brow0 + fr - 256) * 1024; }
    else               { base = Fl; roff = (size_t)(brow0 + fr - 512) * 1024; }
    gptr[c]   = base + roff + kbeg + cg;
    ldsoff[c] = f0 * 32;
  }
  auto stage = [&](short* slotbase, int kt) {
#pragma unroll
    for (int c = 0; c < 6; ++c)
      gload16(gptr[c] + kt * 32, slotbase + ldsoff[c]);
  };

  const int xq = (q ^ ((m15 >> 1) & 3)) * 8;
  int arow[4], brow[4];
#pragma unroll
  for (int i = 0; i < 4; ++i) {
    arow[i] = (wr * 64 + i * 16 + m15) * 32 + xq;
    brow[i] = 8192 + (wc * 64 + i * 16 + m15) * 32 + xq;
  }

  float4_t acc[4][4];
#pragma unroll
  for (int i = 0; i < 4; ++i)
#pragma unroll
    for (int j = 0; j < 4; ++j) acc[i][j] = (float4_t)0.0f;

  stage(&LDS[0][0], 0);
  stage(&LDS[1][0], 1);
  asm volatile("s_waitcnt vmcnt(6)");
  __builtin_amdgcn_s_barrier();

  int cur = 0, st2 = 2;
  for (int t = 0; t < nt; ++t) {
    short* buf = &LDS[cur][0];
    __builtin_amdgcn_sched_barrier(0);

    short8_t ah[4], al[4], bh[4], bl[4];
#pragma unroll
    for (int i = 0; i < 4; ++i) {
      ah[i] = *(const short8_t*)&buf[arow[i]];
      al[i] = *(const short8_t*)&buf[arow[i] + 4096];
    }
#pragma unroll
    for (int j = 0; j < 4; ++j) {
      bh[j] = *(const short8_t*)&buf[brow[j]];
      bl[j] = *(const short8_t*)&buf[brow[j] + 8192];
    }

    if (t + 2 < nt) stage(&LDS[st2][0], t + 2);

    __builtin_amdgcn_s_setprio(1);
#pragma unroll
    for (int i = 0; i < 4; ++i)
#pragma unroll
      for (int j = 0; j < 4; ++j) {
        acc[i][j] = __builtin_amdgcn_mfma_f32_16x16x32_bf16(ah[i], bh[j], acc[i][j], 0, 0, 0);
        acc[i][j] = __builtin_amdgcn_mfma_f32_16x16x32_bf16(ah[i], bl[j], acc[i][j], 0, 0, 0);
        acc[i][j] = __builtin_amdgcn_mfma_f32_16x16x32_bf16(al[i], bh[j], acc[i][j], 0, 0, 0);
      }
    __builtin_amdgcn_s_setprio(0);

    __builtin_amdgcn_sched_barrier(0);
    if (t + 2 < nt) {
      asm volatile("s_waitcnt vmcnt(6)");
    } else if (t + 1 < nt) {
      asm volatile("s_waitcnt vmcnt(0)");
    }
    __builtin_amdgcn_s_barrier();
    cur = (cur == 2) ? 0 : cur + 1;
    st2 = (st2 == 2) ? 0 : st2 + 1;
  }

  float* ep = eparts + (size_t)(zb * 4 + zk) * 65536;
#pragma unroll
  for (int i = 0; i < 4; ++i) {
#pragma unroll
    for (int r = 0; r < 4; ++r) {
      const int gm = sp * 128 + wr * 64 + i * 16 + q * 4 + r;
#pragma unroll
      for (int j = 0; j < 4; ++j) {
        const int gn = wc * 64 + j * 16 + m15;
        ep[(size_t)gm * 256 + gn] = acc[i][j][r];
      }
    }
  }
}

// ---------------------------------------------------------------------------
// betas/alphas GEMM: fp16 NT ring-3, 128x256 tile, 512 threads = 8 waves
// (2M x 4N), BK=32, 3 x 24 KiB LDS (A 128 rows + B 256 rows of 32 fp16),
// 3 gload16/wave/tile -> counted vmcnt(3), nt=8, single tail vmcnt(0).
// grid (8,1,64): bx = mt*4+ntile, z batch. A = attn[z] (z<32) / attnT (z>=32,
// contiguous); B = PHbT[(z^32)] panel (z<32 -> H^T, z>=32 -> P^T).
// Epilogue: fp16 store to Cat right halves.
// ---------------------------------------------------------------------------
__global__ __launch_bounds__(512, 2) void gemm_f16r(
    const _Float16* __restrict__ attn, const _Float16* __restrict__ phbt,
    _Float16* __restrict__ cat)
{
  __shared__ __align__(16) _Float16 LDS[3][12288];   // 3 x 24 KiB

  const int bx = blockIdx.x;
  const int z  = blockIdx.z;
  const int mt = bx >> 2, ntile = bx & 3;
  const int row0 = mt * 128;
  const int col0 = ntile * 256;
  const _Float16* A = attn + (size_t)z * 65536;
  const _Float16* B = phbt + (size_t)(z ^ 32) * 262144 + (size_t)col0 * 256;
  const int tid = threadIdx.x, lane = tid & 63, wave = tid >> 6;
  const int wr = wave >> 2, wc = wave & 3;
  const int m15 = lane & 15, q = lane >> 4;
  const int nt = 8;

  const int cg = ((lane & 3) ^ ((lane >> 3) & 3)) * 8;
  const _Float16* gptr[3];
  int ldsoff[3];
#pragma unroll
  for (int c = 0; c < 3; ++c) {
    const int f0 = wave * 48 + c * 16;
    const int fr = f0 + (lane >> 2);
    if (f0 < 128) gptr[c] = A + (size_t)(row0 + fr) * 256 + cg;
    else          gptr[c] = B + (size_t)(fr - 128) * 256 + cg;
    ldsoff[c] = f0 * 32;
  }
  auto stage = [&](_Float16* slotbase, int kt) {
#pragma unroll
    for (int c = 0; c < 3; ++c)
      gload16(gptr[c] + kt * 32, slotbase + ldsoff[c]);
  };

  const int xq = (q ^ ((m15 >> 1) & 3)) * 8;
  int aoff[4], boff[4];
#pragma unroll
  for (int i = 0; i < 4; ++i) {
    aoff[i] = (wr * 64 + i * 16 + m15) * 32 + xq;
    boff[i] = (128 + wc * 64 + i * 16 + m15) * 32 + xq;
  }

  float4_t acc[4][4];
#pragma unroll
  for (int i = 0; i < 4; ++i)
#pragma unroll
    for (int j = 0; j < 4; ++j) acc[i][j] = (float4_t)0.0f;

  stage(&LDS[0][0], 0);
  stage(&LDS[1][0], 1);
  asm volatile("s_waitcnt vmcnt(3)");
  __builtin_amdgcn_s_barrier();

  int cur = 0, st2 = 2;
  for (int t = 0; t < nt; ++t) {
    _Float16* buf = &LDS[cur][0];
    __builtin_amdgcn_sched_barrier(0);

    half8_t af[4], bf[4];
#pragma unroll
    for (int i = 0; i < 4; ++i) af[i] = *(const half8_t*)&buf[aoff[i]];
#pragma unroll
    for (int j = 0; j < 4; ++j) bf[j] = *(const half8_t*)&buf[boff[j]];

    if (t + 2 < nt) stage(&LDS[st2][0], t + 2);

    __builtin_amdgcn_s_setprio(1);
#pragma unroll
    for (int i = 0; i < 4; ++i)
#pragma unroll
      for (int j = 0; j < 4; ++j)
        acc[i][j] = __builtin_amdgcn_mfma_f32_16x16x32_f16(af[i], bf[j], acc[i][j], 0, 0, 0);
    __builtin_amdgcn_s_setprio(0);

    __builtin_amdgcn_sched_barrier(0);
    if (t + 2 < nt) {
      asm volatile("s_waitcnt vmcnt(3)");
    } else if (t + 1 < nt) {
      asm volatile("s_waitcnt vmcnt(0)");
    }
    __builtin_amdgcn_s_barrier();
    cur = (cur == 2) ? 0 : cur + 1;
    st2 = (st2 == 2) ? 0 : st2 + 1;
  }

  _Float16* Cp = cat + 1024 + (size_t)z * (256 * 2048);
#pragma unroll
  for (int i = 0; i < 4; ++i) {
#pragma unroll
    for (int r = 0; r < 4; ++r) {
      const int gm = row0 + wr * 64 + i * 16 + q * 4 + r;
#pragma unroll
      for (int j = 0; j < 4; ++j) {
        const int gn = col0 + wc * 64 + j * 16 + m15;
        Cp[(size_t)gm * 2048 + gn] = (_Float16)acc[i][j][r];
      }
    }
  }
}

// ---------------------------------------------------------------------------
// V-GEMM: fp16 NT, 256x256 tile, BK=32, 512 threads = 8 waves (2M x 4N),
// 4-deep LDS ring (4 x 32 KiB), tile t+2 staged during tile t, ONE barrier
// per K-tile, counted vmcnt(4). Conflict-free chunk swizzle (0 measured).
// Fused tanh + column-sum epilogue -> agg. (141-161 us band, 43-44% MfmaUtil.)
// ---------------------------------------------------------------------------
__global__ __launch_bounds__(512, 2) void gemm_f16_sum8(
    const _Float16* __restrict__ A, int lda,
    const _Float16* __restrict__ B, int ldb,
    int K, float* __restrict__ agg)
{
  __shared__ __align__(16) _Float16 LDS[4][2 * 256 * 32];

  const int row0 = blockIdx.x * 256;
  const int col0 = blockIdx.y * 256;
  const int tid  = threadIdx.x;
  const int lane = tid & 63, wave = tid >> 6;
  const int wr = wave >> 2, wc = wave & 3;     // 2 M-waves x 4 N-waves
  const int m15 = lane & 15, q = lane >> 4;
  const int nt = K / 32;

  const int srow = wave * 32 + (lane >> 2);
  const int cg   = ((lane & 3) ^ ((lane >> 3) & 3)) * 8;
  const _Float16* gA = A + (size_t)(row0 + srow) * lda + cg;
  const _Float16* gB = B + (size_t)(col0 + srow) * ldb + cg;

  auto stageA = [&](int t) {
    const _Float16* g = gA + t * 32;
    _Float16* l = &LDS[t & 3][wave * 1024];
    gload16(g, l);
    gload16(g + (size_t)16 * lda, l + 512);
  };
  auto stageB = [&](int t) {
    const _Float16* g = gB + t * 32;
    _Float16* l = &LDS[t & 3][8192 + wave * 1024];
    gload16(g, l);
    gload16(g + (size_t)16 * ldb, l + 512);
  };

  const int xq = (q ^ ((m15 >> 1) & 3)) * 8;
  int aoff[8], boff[4];
#pragma unroll
  for (int i = 0; i < 8; ++i)
    aoff[i] = (wr * 128 + i * 16 + m15) * 32 + xq;
#pragma unroll
  for (int j = 0; j < 4; ++j)
    boff[j] = 8192 + (wc * 64 + j * 16 + m15) * 32 + xq;

  float4_t acc[8][4];
#pragma unroll
  for (int i = 0; i < 8; ++i)
#pragma unroll
    for (int j = 0; j < 4; ++j) acc[i][j] = (float4_t)0.0f;

  stageA(0); stageB(0);
  stageA(1); stageB(1);
  asm volatile("s_waitcnt vmcnt(4)");
  __builtin_amdgcn_s_barrier();

  for (int t = 0; t < nt; ++t) {
    const _Float16* buf = &LDS[t & 3][0];
    __builtin_amdgcn_sched_barrier(0);

    half8_t a0[4], a1[4], bb[4];
#pragma unroll
    for (int i = 0; i < 4; ++i) a0[i] = *(const half8_t*)&buf[aoff[i]];
#pragma unroll
    for (int j = 0; j < 4; ++j) bb[j] = *(const half8_t*)&buf[boff[j]];
#pragma unroll
    for (int i = 0; i < 4; ++i) a1[i] = *(const half8_t*)&buf[aoff[4 + i]];

    if (t + 2 < nt) { stageA(t + 2); stageB(t + 2); }

    __builtin_amdgcn_s_setprio(1);
#pragma unroll
    for (int i = 0; i < 4; ++i)
#pragma unroll
      for (int j = 0; j < 4; ++j)
        acc[i][j] = __builtin_amdgcn_mfma_f32_16x16x32_f16(a0[i], bb[j], acc[i][j], 0, 0, 0);
#pragma unroll
    for (int i = 0; i < 4; ++i)
#pragma unroll
      for (int j = 0; j < 4; ++j)
        acc[4 + i][j] = __builtin_amdgcn_mfma_f32_16x16x32_f16(a1[i], bb[j], acc[4 + i][j], 0, 0, 0);
    __builtin_amdgcn_s_setprio(0);

    __builtin_amdgcn_sched_barrier(0);
    if (t + 2 < nt) {
      asm volatile("s_waitcnt vmcnt(4)");
    } else if (t + 1 < nt) {
      asm volatile("s_waitcnt vmcnt(0)");
    }
    __builtin_amdgcn_s_barrier();
  }

  // ---- epilogue: tanh + column-sum -> agg[b][half*2048 + col] ----
  const int half_ = row0 >= 8192;
  const int b     = (row0 & 8191) >> 8;
#pragma unroll
  for (int j = 0; j < 4; ++j) {
    float s = 0.0f;
#pragma unroll
    for (int i = 0; i < 8; ++i)
#pragma unroll
      for (int r = 0; r < 4; ++r) s += fast_tanh(acc[i][j][r]);
    s += __shfl_xor(s, 16);
    s += __shfl_xor(s, 32);
    if (q == 0) {
      int col = col0 + wc * 64 + j * 16 + m15;
      atomicAdd(&agg[(size_t)b * 4096 + half_ * 2048 + col], s);
    }
  }
}

// ---------------------------------------------------------------------------
// Merged weight transpose: blocks 0..1023 = W_F [1024][1024] -> split bf16
// transpose; blocks 1024..5119 = W_G [2048][2048] -> fp16 transpose.
// ---------------------------------------------------------------------------
__global__ __launch_bounds__(256) void transpose_w(
    const float* __restrict__ WF, short* __restrict__ oh, short* __restrict__ ol,
    const float* __restrict__ WG, _Float16* __restrict__ og)
{
  __shared__ float tile[32][33];
  const int id = blockIdx.x;
  const int tx = threadIdx.x & 31, ty = threadIdx.x >> 5;
  if (id < 1024) {
    const int c0 = (id & 31) * 32, r0 = (id >> 5) * 32;   // over [1024][1024]
#pragma unroll
    for (int i = 0; i < 4; ++i) {
      int r = ty + i * 8;
      tile[r][tx] = WF[(size_t)(r0 + r) * 1024 + c0 + tx];
    }
    __syncthreads();
#pragma unroll
    for (int i = 0; i < 4; ++i) {
      int cc = ty + i * 8;
      float v = tile[tx][cc];
      short hi, lo; split2(v, hi, lo);
      size_t o = (size_t)(c0 + cc) * 1024 + r0 + tx;
      oh[o] = hi;
      ol[o] = lo;
    }
  } else {
    const int t2 = id - 1024;
    const int c0 = (t2 & 63) * 32, r0 = (t2 >> 6) * 32;   // over [2048][2048]
#pragma unroll
    for (int i = 0; i < 4; ++i) {
      int r = ty + i * 8;
      tile[r][tx] = WG[(size_t)(r0 + r) * 2048 + c0 + tx];
    }
    __syncthreads();
#pragma unroll
    for (int i = 0; i < 4; ++i) {
      int cc = ty + i * 8;
      og[(size_t)(c0 + cc) * 2048 + r0 + tx] = (_Float16)tile[tx][cc];
    }
  }
}

// --- fp16 [256x256] batched transpose (attn -> attnT) ---
__global__ __launch_bounds__(256) void transpose_b2b(
    const short* __restrict__ in, short* __restrict__ out,
    int R, int C, long sIn, long sOut)
{
  __shared__ short tile[32][33];
  in  += (size_t)blockIdx.z * sIn;
  out += (size_t)blockIdx.z * sOut;
  const int tx = threadIdx.x & 31, ty = threadIdx.x >> 5;
  const int c0 = blockIdx.x * 32, r0 = blockIdx.y * 32;
#pragma unroll
  for (int i = 0; i < 4; ++i) {
    int r = ty + i * 8;
    tile[r][tx] = in[(size_t)(r0 + r) * C + c0 + tx];
  }
  __syncthreads();
#pragma unroll
  for (int i = 0; i < 4; ++i) {
    int cc = ty + i * 8;
    out[(size_t)(c0 + cc) * R + r0 + tx] = tile[tx][cc];
  }
}

// ---------------------------------------------------------------------------
// Fused input conversion + transpose, vectorized. One pass over P/H producing
// (a) split bf16 planes, (b) fp16 Cat left half, (c) fp16 per-batch transpose
// PHbT[z][1024][256] (z<32 = P^T, z>=32 = H^T). Also zeros agg (512 KB) as a
// side task of the first 128 blocks.
// grid (16, 4, 64): x = 64-col tile over 1024, y = 64-row tile over 256.
// ---------------------------------------------------------------------------
__global__ __launch_bounds__(256) void conv_in_t(
    const float* __restrict__ P, const float* __restrict__ Hh,
    short* __restrict__ oh, short* __restrict__ ol,
    _Float16* __restrict__ cat, _Float16* __restrict__ phbt,
    float* __restrict__ agg)
{
  __shared__ __align__(16) float tile[64][68];   // 272B rows, 16B-aligned
  const int zb   = blockIdx.z;
  const int half = zb >> 5, b = zb & 31;
  const int bid = (zb * 4 + blockIdx.y) * 16 + blockIdx.x;
  if (bid < 128) {
    float4_t zz = (float4_t)0.0f;
    *(float4_t*)&agg[(size_t)bid * 1024 + threadIdx.x * 4] = zz;
  }
  const float* in = (half ? Hh : P) + (size_t)b * 256 * 1024;
  const int c0 = blockIdx.x * 64;   // col in [0,1024)
  const int r0 = blockIdx.y * 64;   // row in [0,256)
  const int t  = threadIdx.x;
  const int rl = t >> 4;            // 0..15
  const int c4 = (t & 15) * 4;      // 0,4,...,60
  const size_t rowbase = (size_t)half * 8192 + (size_t)b * 256;
#pragma unroll
  for (int i = 0; i < 4; ++i) {
    int r = rl + i * 16;
    float4 v = *(const float4*)&in[(size_t)(r0 + r) * 1024 + c0 + c4];
    *(float4*)&tile[r][c4] = v;
    short4 h, l;
    split2(v.x, h.x, l.x); split2(v.y, h.y, l.y);
    split2(v.z, h.z, l.z); split2(v.w, h.w, l.w);
    size_t o = (rowbase + r0 + r) * 1024 + c0 + c4;
    *(short4*)&oh[o] = h;
    *(short4*)&ol[o] = l;
    half4_t c16;
    c16.x = (_Float16)v.x; c16.y = (_Float16)v.y;
    c16.z = (_Float16)v.z; c16.w = (_Float16)v.w;
    *(half4_t*)&cat[(rowbase + r0 + r) * 2048 + c0 + c4] = c16;
  }
  __syncthreads();
  _Float16* op = phbt + (size_t)zb * 1024 * 256;
  const int tx = t & 31;            // row-pair index: rows 2tx, 2tx+1
  const int w  = t >> 5;            // 0..7
#pragma unroll
  for (int i = 0; i < 8; ++i) {
    int cc = w + i * 8;             // 0..63
    half2_t p;
    p.x = (_Float16)tile[tx * 2][cc];
    p.y = (_Float16)tile[tx * 2 + 1][cc];
    *(half2_t*)&op[(size_t)(c0 + cc) * 256 + r0 + tx * 2] = p;
  }
}

// --- softmax over rows of 256, summing 4 E split-K slice panels,
//     fp32 -> fp16. eparts layout: [zb*4+zk][256][256]. ---
__global__ __launch_bounds__(256) void softmax_rows(
    const float* __restrict__ e, _Float16* __restrict__ attn)
{
  const int row  = blockIdx.x * 4 + (threadIdx.x >> 6);   // 0..8191
  const int lane = threadIdx.x & 63;
  const size_t base = ((size_t)(row >> 8) * 4) * 65536
                    + (size_t)(row & 255) * 256 + lane * 4;
  const float4 v0 = *(const float4*)&e[base];
  const float4 v1 = *(const float4*)&e[base + 65536];
  const float4 v2 = *(const float4*)&e[base + 2 * 65536];
  const float4 v3 = *(const float4*)&e[base + 3 * 65536];
  float4 v;
  v.x = (v0.x + v1.x) + (v2.x + v3.x);
  v.y = (v0.y + v1.y) + (v2.y + v3.y);
  v.z = (v0.z + v1.z) + (v2.z + v3.z);
  v.w = (v0.w + v1.w) + (v2.w + v3.w);
  float m = fmaxf(fmaxf(v.x, v.y), fmaxf(v.z, v.w));
#pragma unroll
  for (int off = 32; off; off >>= 1) m = fmaxf(m, __shfl_xor(m, off));
  float e0 = __expf(v.x - m), e1 = __expf(v.y - m);
  float e2 = __expf(v.z - m), e3 = __expf(v.w - m);
  float s = e0 + e1 + e2 + e3;
#pragma unroll
  for (int off = 32; off; off >>= 1) s += __shfl_xor(s, off);
  float inv = 1.0f / s;
  half4_t o;
  o.x = (_Float16)(e0 * inv); o.y = (_Float16)(e1 * inv);
  o.z = (_Float16)(e2 * inv); o.w = (_Float16)(e3 * inv);
  *(half4_t*)&attn[(size_t)row * 256 + lane * 4] = o;
}

// ---------------------------------------------------------------------------
// Skinny fp32 GEMM, split-K per-slice panels (no atomics, no pre-zero):
// outp[slice][32][N] = A[32][k-slice] @ B[k-slice][N].
// grid (N/64, K/256); block 256. A-slice transposed in LDS [k][m] (+1 pad).
// ---------------------------------------------------------------------------
__global__ __launch_bounds__(256) void skinny_gemm(
    const float* __restrict__ A, const float* __restrict__ B,
    float* __restrict__ outp, int N, int K)
{
  __shared__ float Asl[256][33];
  const int n0 = blockIdx.x * 64;
  const int k0 = blockIdx.y * 256;
  const int t  = threadIdx.x;
#pragma unroll
  for (int j = 0; j < 32; ++j) {
    Asl[t][j] = A[(size_t)j * K + k0 + t];
  }
  __syncthreads();
  const int l = t & 63, w = t >> 6;
  const int n = n0 + l;
  float acc[8] = {0.f, 0.f, 0.f, 0.f, 0.f, 0.f, 0.f, 0.f};
  const float* Bp = B + (size_t)k0 * N + n;
#pragma unroll 4
  for (int k = 0; k < 256; ++k) {
    float bv = Bp[(size_t)k * N];
#pragma unroll
    for (int m = 0; m < 8; ++m)
      acc[m] += Asl[k][w * 8 + m] * bv;
  }
  float* o = outp + (size_t)blockIdx.y * 32 * N;
#pragma unroll
  for (int m = 0; m < 8; ++m)
    o[(size_t)(w * 8 + m) * N + n] = acc[m];
}

// --- a1 = tanh(sum_slices(parts) + bias), fp32 out ---
__global__ __launch_bounds__(256) void bias_sum_tanh(
    const float* __restrict__ parts, int nslice,
    const float* __restrict__ bias, float* __restrict__ o, int n)
{
  int i = blockIdx.x * 256 + threadIdx.x;
  if (i < n) {
    float s = 0.0f;
    for (int sl = 0; sl < nslice; ++sl) s += parts[(size_t)sl * n + i];
    o[i] = fast_tanh(s + bias[i & 2047]);
  }
}

// --- logits: out[b][0..2] = tanh(sum_8slices(c2parts)[b]+b2) @ W3 + b3 ---
__global__ __launch_bounds__(256) void logits2(
    const float* __restrict__ c2parts, const float* __restrict__ b2,
    const float* __restrict__ W3, const float* __restrict__ b3,
    float* __restrict__ out)
{
  const int b = blockIdx.x, t = threadIdx.x;
  float p0 = 0.f, p1 = 0.f, p2 = 0.f;
  for (int k = t; k < 2048; k += 256) {
    float c = 0.0f;
#pragma unroll
    for (int sl = 0; sl < 8; ++sl) c += c2parts[(size_t)sl * 65536 + b * 2048 + k];
    float a = fast_tanh(c + b2[k]);
    p0 += a * W3[k * 3 + 0];
    p1 += a * W3[k * 3 + 1];
    p2 += a * W3[k * 3 + 2];
  }
#pragma unroll
  for (int off = 32; off; off >>= 1) {
    p0 += __shfl_xor(p0, off);
    p1 += __shfl_xor(p1, off);
    p2 += __shfl_xor(p2, off);
  }
  __shared__ float red[4][3];
  if ((t & 63) == 0) {
    red[t >> 6][0] = p0; red[t >> 6][1] = p1; red[t >> 6][2] = p2;
  }
  __syncthreads();
  if (t < 3) out[b * 3 + t] = b3[t] + red[0][t] + red[1][t] + red[2][t] + red[3][t];
}

extern "C" void kernel_launch(void* const* d_in, const int* in_sizes, int n_in,
                              void* d_out, int out_size, void* d_ws, size_t ws_size,
                              hipStream_t stream) {
  (void)in_sizes; (void)n_in; (void)out_size; (void)ws_size;
  const float* P   = (const float*)d_in[0];
  const float* H   = (const float*)d_in[1];
  const float* W_F = (const float*)d_in[2];
  const float* W_G = (const float*)d_in[3];
  const float* W1  = (const float*)d_in[4];
  const float* b1  = (const float*)d_in[5];
  const float* W2  = (const float*)d_in[6];
  const float* b2  = (const float*)d_in[7];
  const float* W3  = (const float*)d_in[8];
  const float* b3  = (const float*)d_in[9];
  float* out = (float*)d_out;

  char* wsp = (char*)d_ws;
  auto alloc = [&](size_t bytes) {
    char* p = wsp;
    wsp += (bytes + 255) & ~(size_t)255;
    return p;
  };
  short*    Pp_h  = (short*)alloc(16384ull * 1024 * 2);     // [P;H] split planes
  short*    Pp_l  = (short*)alloc(16384ull * 1024 * 2);
  _Float16* Cat16 = (_Float16*)alloc(16384ull * 2048 * 2);  // [P|betas ; H|alphas]
  short*    Fbuf  = (short*)alloc(32ull * 1024 * 1024 * 2); // 64 MB: F planes
  _Float16* PHbT  = (_Float16*)alloc(64ull * 1024 * 256 * 2); // 32 MB: P^T|H^T fp16
  short*    WFT_h = (short*)alloc(1024ull * 1024 * 2);
  short*    WFT_l = (short*)alloc(1024ull * 1024 * 2);
  _Float16* WGT16 = (_Float16*)alloc(2048ull * 2048 * 2);
  _Float16* attn  = (_Float16*)alloc(32ull * 256 * 256 * 2);
  _Float16* attnT = (_Float16*)alloc(32ull * 256 * 256 * 2);
  float*    agg   = (float*)alloc(32ull * 4096 * 4);
  float*    a1f   = (float*)alloc(32ull * 2048 * 4);

  short* F_h = Fbuf;
  short* F_l = Fbuf + 16384ull * 1024;
  // Aliases into Pp planes (dead after the F-projection, step 2):
  float* eparts  = (float*)Pp_h;                       // 32 MB <= 33.5 MB
  float* c1parts = (float*)Pp_l;                       // 16 x 32 x 2048 fp32
  float* c2parts = (float*)(Pp_l + 4ull * 1024 * 1024);// 8 x 32 x 2048 fp32

  // 1. fused input conversion + per-batch transpose (+agg zero); W transposes
  conv_in_t<<<dim3(16, 4, 64), 256, 0, stream>>>(P, H, Pp_h, Pp_l, Cat16, PHbT, agg);
  transpose_w<<<5120, 256, 0, stream>>>(W_F, WFT_h, WFT_l, W_G, WGT16);

  // 2. F = tanh([P;H] @ W_F), split bf16x3, ring-3 counted-vmcnt kernel
  gemm_split_f<<<512, 512, 0, stream>>>(Pp_h, Pp_l, WFT_h, WFT_l, F_h, F_l);

  // 3. scores E[z] = F_p[z] @ F_h[z]^T, split bf16x3, ring-3 kernel,
  //    split-K x4 into per-slice panels (softmax sums the 4 slices)
  gemm_split_e<<<256, 512, 0, stream>>>(F_h, F_l, eparts);

  // 4. softmax (sums 4 E slices) -> fp16 attn; attn^T
  softmax_rows<<<2048, 256, 0, stream>>>(eparts, attn);
  transpose_b2b<<<dim3(8, 8, 32), 256, 0, stream>>>(
      (const short*)attn, (short*)attnT, 256, 256, 65536, 65536);

  // 5. betas (z<32) and alphas (z>=32) in ONE launch, ring-3 fp16 kernel
  gemm_f16r<<<dim3(8, 1, 64), 512, 0, stream>>>(attn, PHbT, Cat16);

  // 6. V = tanh(Cat @ W_G) fused column-sum -> agg
  gemm_f16_sum8<<<dim3(64, 8, 1), 512, 0, stream>>>(
      Cat16, 2048, WGT16, 2048, 2048, agg);

  // 7. classifier: fp32 skinny split-K GEMMs, per-slice panels, no atomics
  skinny_gemm<<<dim3(32, 16), 256, 0, stream>>>(agg, W1, c1parts, 2048, 4096);
  bias_sum_tanh<<<256, 256, 0, stream>>>(c1parts, 16, b1, a1f, 32 * 2048);
  skinny_gemm<<<dim3(32, 8), 256, 0, stream>>>(a1f, W2, c2parts, 2048, 2048);
  logits2<<<32, 256, 0, stream>>>(c2parts, b2, W3, b3, out);
}